// Round 1
// baseline (331.631 us; speedup 1.0000x reference)
//
#include <hip/hip_runtime.h>

// Problem dims
#define Bb 8
#define Gg 512
#define Kk 64
#define Nn 1024
#define Mm 128

struct P7 { const float* p[7]; };

// ---------------------------------------------------------------------------
// K0: transpose seven 128x128 weight matrices into ws (WT[h][m] = W[m][h])
// ---------------------------------------------------------------------------
__global__ __launch_bounds__(256) void transpose7(P7 ptrs, float* __restrict__ outT) {
  __shared__ float tile[32][33];
  const int mat = blockIdx.z;
  const float* src = ptrs.p[mat];
  float* dst = outT + (size_t)mat * Mm * Mm;
  const int tx = threadIdx.x, ty = threadIdx.y;
  const int xo = blockIdx.x * 32, y0 = blockIdx.y * 32;
  for (int j = ty; j < 32; j += 8) tile[j][tx] = src[(size_t)(y0 + j) * Mm + xo + tx];
  __syncthreads();
  for (int j = ty; j < 32; j += 8) dst[(size_t)(xo + j) * Mm + y0 + tx] = tile[tx][j];
}

// ---------------------------------------------------------------------------
// K1: single pass over z. Computes:
//   ra[b,g,m]   = (sum_k e*hs_key)/(sum_k e)          (finalized per g)
//   att[b,g,k]  = sum_m z*z1w[m]                       (bias dropped: cancels)
//   laNum/laDen partials per g-chunk of 16             (reduced in K2)
// grid: B*32 blocks of 1024 threads. thread: m4=(t&31)*4, kgrp=t>>5 (k=2*kgrp+i)
// ---------------------------------------------------------------------------
__global__ __launch_bounds__(1024) void k1_stream_z(
    const float* __restrict__ z, const float* __restrict__ hs_grid,
    const float* __restrict__ hs_key, const float* __restrict__ z1w,
    float* __restrict__ raOut, float* __restrict__ attOut,
    float* __restrict__ laNum, float* __restrict__ laDen)
{
  __shared__ __align__(16) float s_hskey[Kk * Mm];    // 32 KB
  __shared__ __align__(16) float s_hsgrid[16 * Mm];   // 8 KB
  __shared__ __align__(16) float s_rn[16 * Mm];       // 8 KB
  __shared__ __align__(16) float s_rd[16 * Mm];       // 8 KB

  const int t = threadIdx.x;
  const int b = blockIdx.x >> 5;
  const int gblk = blockIdx.x & 31;
  const int lane_m = t & 31;
  const int m4 = lane_m << 2;
  const int kgrp = t >> 5;   // 0..31
  const int w = t >> 6;      // wave 0..15

  const float* hkb = hs_key + (size_t)b * Kk * Mm;
  for (int idx = t; idx < Kk * Mm; idx += 1024) s_hskey[idx] = hkb[idx];
  const float* hgb = hs_grid + ((size_t)b * Gg + gblk * 16) * Mm;
  for (int idx = t; idx < 16 * Mm; idx += 1024) s_hsgrid[idx] = hgb[idx];

  const float zw0 = z1w[m4], zw1 = z1w[m4 + 1], zw2 = z1w[m4 + 2], zw3 = z1w[m4 + 3];

  float la_n[2][4], la_d[2][4];
#pragma unroll
  for (int i = 0; i < 2; ++i)
#pragma unroll
    for (int j = 0; j < 4; ++j) { la_n[i][j] = 0.f; la_d[i][j] = 0.f; }

  __syncthreads();

  for (int gl = 0; gl < 16; ++gl) {
    const int g = gblk * 16 + gl;
    const float* zp = z + (((size_t)b * Gg + g) * Kk) * Mm;
    const float4 hg = *reinterpret_cast<const float4*>(s_hsgrid + gl * Mm + m4);
    float rn0 = 0, rn1 = 0, rn2 = 0, rn3 = 0, rd0 = 0, rd1 = 0, rd2 = 0, rd3 = 0;
#pragma unroll
    for (int i = 0; i < 2; ++i) {
      const int k = kgrp * 2 + i;
      const float4 v = *reinterpret_cast<const float4*>(zp + k * Mm + m4);
      const float e0 = __expf(v.x), e1 = __expf(v.y), e2 = __expf(v.z), e3 = __expf(v.w);
      la_n[i][0] += e0 * hg.x; la_n[i][1] += e1 * hg.y; la_n[i][2] += e2 * hg.z; la_n[i][3] += e3 * hg.w;
      la_d[i][0] += e0;        la_d[i][1] += e1;        la_d[i][2] += e2;        la_d[i][3] += e3;
      const float4 hk = *reinterpret_cast<const float4*>(s_hskey + k * Mm + m4);
      rn0 += e0 * hk.x; rn1 += e1 * hk.y; rn2 += e2 * hk.z; rn3 += e3 * hk.w;
      rd0 += e0; rd1 += e1; rd2 += e2; rd3 += e3;
      float ap = v.x * zw0 + v.y * zw1 + v.z * zw2 + v.w * zw3;
      ap += __shfl_xor(ap, 16); ap += __shfl_xor(ap, 8); ap += __shfl_xor(ap, 4);
      ap += __shfl_xor(ap, 2);  ap += __shfl_xor(ap, 1);
      if (lane_m == 0) attOut[((size_t)b * Gg + g) * Kk + k] = ap;
    }
    // reduce ra partials across the 32 kgrps: first pair waves' halves
    rn0 += __shfl_xor(rn0, 32); rn1 += __shfl_xor(rn1, 32); rn2 += __shfl_xor(rn2, 32); rn3 += __shfl_xor(rn3, 32);
    rd0 += __shfl_xor(rd0, 32); rd1 += __shfl_xor(rd1, 32); rd2 += __shfl_xor(rd2, 32); rd3 += __shfl_xor(rd3, 32);
    if ((t & 63) < 32) {
      float4 a = make_float4(rn0, rn1, rn2, rn3);
      float4 d = make_float4(rd0, rd1, rd2, rd3);
      *reinterpret_cast<float4*>(s_rn + w * Mm + m4) = a;
      *reinterpret_cast<float4*>(s_rd + w * Mm + m4) = d;
    }
    __syncthreads();
    if (t < Mm) {
      float num = 0.f, den = 0.f;
#pragma unroll
      for (int ww = 0; ww < 16; ++ww) { num += s_rn[ww * Mm + t]; den += s_rd[ww * Mm + t]; }
      raOut[((size_t)b * Gg + g) * Mm + t] = num / den;
    }
    __syncthreads();
  }

  const size_t base = (((size_t)b * 32 + gblk) * Kk) * Mm;
#pragma unroll
  for (int i = 0; i < 2; ++i) {
    const int k = kgrp * 2 + i;
    float4 n4 = make_float4(la_n[i][0], la_n[i][1], la_n[i][2], la_n[i][3]);
    float4 d4 = make_float4(la_d[i][0], la_d[i][1], la_d[i][2], la_d[i][3]);
    *reinterpret_cast<float4*>(laNum + base + k * Mm + m4) = n4;
    *reinterpret_cast<float4*>(laDen + base + k * Mm + m4) = d4;
  }
}

// ---------------------------------------------------------------------------
// K2: la[b,k,m] = (sum_p num_p) / (sum_p den_p)   over 32 g-chunk partials
// ---------------------------------------------------------------------------
__global__ __launch_bounds__(256) void k2_reduce_la(
    const float* __restrict__ laNum, const float* __restrict__ laDen,
    float* __restrict__ la)
{
  const int idx = blockIdx.x * 256 + threadIdx.x;   // B*K*M = 65536
  const int b = idx >> 13;
  const int r = idx & 8191;
  const float* np = laNum + (size_t)b * 32 * 8192 + r;
  const float* dp = laDen + (size_t)b * 32 * 8192 + r;
  float num = 0.f, den = 0.f;
#pragma unroll 8
  for (int p = 0; p < 32; ++p) { num += np[p * 8192]; den += dp[p * 8192]; }
  la[idx] = num / den;
}

// ---------------------------------------------------------------------------
// K3: att_l partials: attl_part[b,p,k] = sum over 64 g's of softmax_k(att[b,g,:])
// block = (b, p); 4 waves, lane = k
// ---------------------------------------------------------------------------
__global__ __launch_bounds__(256) void k3_attl(const float* __restrict__ att,
                                               float* __restrict__ attl_part)
{
  const int b = blockIdx.x >> 3, p = blockIdx.x & 7;
  const int t = threadIdx.x;
  const int w = t >> 6, lane = t & 63;
  float acc = 0.f;
  for (int j = 0; j < 16; ++j) {
    const int g = p * 64 + w * 16 + j;
    const float a = att[((size_t)b * Gg + g) * Kk + lane];
    float mx = a;
    for (int off = 32; off; off >>= 1) mx = fmaxf(mx, __shfl_xor(mx, off));
    const float e = __expf(a - mx);
    float s = e;
    for (int off = 32; off; off >>= 1) s += __shfl_xor(s, off);
    acc += e / s;
  }
  __shared__ float sred[4][64];
  sred[w][lane] = acc;
  __syncthreads();
  if (t < 64) attl_part[(b * 8 + p) * 64 + t] = sred[0][t] + sred[1][t] + sred[2][t] + sred[3][t];
}

// ---------------------------------------------------------------------------
// K4a: column (over g) online max/sum partials per (b, gc, k)
// ---------------------------------------------------------------------------
__global__ __launch_bounds__(256) void k4a_attr_ms(const float* __restrict__ att,
                                                   float* __restrict__ pm, float* __restrict__ ps)
{
  const int b = blockIdx.x >> 3, gc = blockIdx.x & 7;
  const int t = threadIdx.x;
  const int k = t & 63, j4 = t >> 6;
  float m = -1e30f, s = 0.f;
  for (int j = 0; j < 16; ++j) {
    const int g = gc * 64 + j4 * 16 + j;
    const float a = att[((size_t)b * Gg + g) * Kk + k];
    if (a > m) { s = s * __expf(m - a) + 1.0f; m = a; }
    else s += __expf(a - m);
  }
  __shared__ float sm[4][64], ss[4][64];
  sm[j4][k] = m; ss[j4][k] = s;
  __syncthreads();
  if (t < 64) {
    float M = sm[0][t];
    for (int q = 1; q < 4; ++q) M = fmaxf(M, sm[q][t]);
    float S = 0.f;
    for (int q = 0; q < 4; ++q) S += ss[q][t] * __expf(sm[q][t] - M);
    pm[(b * 8 + gc) * 64 + t] = M;
    ps[(b * 8 + gc) * 64 + t] = S;
  }
}

// K4b: att_r[b,g] = sum_k exp(a - Mx[k]) / S[k]
__global__ __launch_bounds__(256) void k4b_attr(const float* __restrict__ att,
                                                const float* __restrict__ pm, const float* __restrict__ ps,
                                                float* __restrict__ att_r)
{
  const int b = blockIdx.x >> 3, gc = blockIdx.x & 7;
  const int t = threadIdx.x;
  const int k = t & 63, grp = t >> 6;
  __shared__ float Mx[64], S[64];
  if (t < 64) {
    float M = -1e30f;
    for (int p = 0; p < 8; ++p) M = fmaxf(M, pm[(b * 8 + p) * 64 + t]);
    float s = 0.f;
    for (int p = 0; p < 8; ++p) s += ps[(b * 8 + p) * 64 + t] * __expf(pm[(b * 8 + p) * 64 + t] - M);
    Mx[t] = M; S[t] = s;
  }
  __syncthreads();
  const float Mk = Mx[k], Sk = S[k];
  for (int j = 0; j < 16; ++j) {
    const int g = gc * 64 + grp * 16 + j;
    float p = __expf(att[((size_t)b * Gg + g) * Kk + k] - Mk) / Sk;
    for (int off = 32; off; off >>= 1) p += __shfl_xor(p, off);
    if (k == 0) att_r[b * Gg + g] = p;
  }
}

// ---------------------------------------------------------------------------
// K5: generic linear: out[r,m] = sum_h in1[r,h]*W1T[h,m] (+ in2[r,h]*W2T[h,m]) + b1 (+ b2)
// 16 rows per block, 256 threads: m = t&127, h-half = t>>7
// ---------------------------------------------------------------------------
__global__ __launch_bounds__(256) void k5_linear2(
    const float* __restrict__ in1, const float* __restrict__ W1T,
    const float* __restrict__ in2, const float* __restrict__ W2T,
    const float* __restrict__ b1, const float* __restrict__ b2,
    float* __restrict__ out)
{
  __shared__ float s1[16][Mm];
  __shared__ float s2[16][Mm];
  __shared__ float sacc[16][Mm];
  const int r0 = blockIdx.x * 16;
  const int t = threadIdx.x;
  const int m = t & 127, hh = t >> 7;
  for (int idx = t; idx < 16 * Mm; idx += 256) s1[idx >> 7][idx & 127] = in1[(size_t)r0 * Mm + idx];
  if (in2) for (int idx = t; idx < 16 * Mm; idx += 256) s2[idx >> 7][idx & 127] = in2[(size_t)r0 * Mm + idx];
  __syncthreads();
  float acc[16];
#pragma unroll
  for (int r = 0; r < 16; ++r) acc[r] = 0.f;
  const int h0 = hh * 64;
  if (in2) {
    for (int h = h0; h < h0 + 64; ++h) {
      const float w1 = W1T[(size_t)h * Mm + m];
      const float w2 = W2T[(size_t)h * Mm + m];
#pragma unroll
      for (int r = 0; r < 16; ++r) acc[r] += s1[r][h] * w1 + s2[r][h] * w2;
    }
  } else {
    for (int h = h0; h < h0 + 64; ++h) {
      const float w1 = W1T[(size_t)h * Mm + m];
#pragma unroll
      for (int r = 0; r < 16; ++r) acc[r] += s1[r][h] * w1;
    }
  }
  if (hh == 1) {
#pragma unroll
    for (int r = 0; r < 16; ++r) sacc[r][m] = acc[r];
  }
  __syncthreads();
  if (hh == 0) {
    const float bias = b1[m] + (b2 ? b2[m] : 0.f);
#pragma unroll
    for (int r = 0; r < 16; ++r) out[(size_t)(r0 + r) * Mm + m] = acc[r] + sacc[r][m] + bias;
  }
}

// ---------------------------------------------------------------------------
// K6a: scores[b,n,k] = mask ? w_Rl * dot(Rh[n,:], lh[k,:]) : -1e10
// block = (b, 16-n tile); t: k = t&63, h-split = t>>6
// ---------------------------------------------------------------------------
__global__ __launch_bounds__(256) void k6a_scores(
    const float* __restrict__ Rh, const float* __restrict__ lh,
    const int* __restrict__ mask, const float* __restrict__ wRl,
    float* __restrict__ scores)
{
  __shared__ float s_rh[16][Mm];
  __shared__ float s_lh[64][Mm + 1];
  __shared__ float s_acc[4][16][64];
  const int b = blockIdx.x >> 6;
  const int n0 = (blockIdx.x & 63) * 16;
  const int t = threadIdx.x;
  const int k = t & 63, hs = t >> 6;
  for (int idx = t; idx < 16 * Mm; idx += 256)
    s_rh[idx >> 7][idx & 127] = Rh[((size_t)b * Nn + n0) * Mm + idx];
  for (int idx = t; idx < 64 * Mm; idx += 256)
    s_lh[idx >> 7][idx & 127] = lh[(size_t)b * Kk * Mm + idx];
  __syncthreads();
  float acc[16];
#pragma unroll
  for (int r = 0; r < 16; ++r) acc[r] = 0.f;
  for (int h = hs * 32; h < hs * 32 + 32; ++h) {
    const float lv = s_lh[k][h];
#pragma unroll
    for (int r = 0; r < 16; ++r) acc[r] += s_rh[r][h] * lv;
  }
#pragma unroll
  for (int r = 0; r < 16; ++r) s_acc[hs][r][k] = acc[r];
  __syncthreads();
  const float wv = wRl[0];
  for (int q = 0; q < 4; ++q) {
    const int idx = q * 256 + t;
    const int r = idx >> 6, kk = idx & 63;
    float v = s_acc[0][r][kk] + s_acc[1][r][kk] + s_acc[2][r][kk] + s_acc[3][r][kk];
    v = (mask[b * Kk + kk] == 0) ? -1e10f : wv * v;
    scores[((size_t)b * Nn + n0 + r) * Kk + kk] = v;
  }
}

// K6b: softmax over n (in place). block per b; t: k=t&63, n-chunk=t>>6
__global__ __launch_bounds__(256) void k6b_softmax_n(float* __restrict__ scores) {
  const int b = blockIdx.x;
  const int t = threadIdx.x;
  const int k = t & 63, nc = t >> 6;
  float m = -1e30f, s = 0.f;
  for (int j = 0; j < 256; ++j) {
    const int n = nc * 256 + j;
    const float a = scores[((size_t)b * Nn + n) * Kk + k];
    if (a > m) { s = s * __expf(m - a) + 1.0f; m = a; }
    else s += __expf(a - m);
  }
  __shared__ float sm[4][64], ss[4][64], Mx[64], S[64];
  sm[nc][k] = m; ss[nc][k] = s;
  __syncthreads();
  if (t < 64) {
    float M = fmaxf(fmaxf(sm[0][t], sm[1][t]), fmaxf(sm[2][t], sm[3][t]));
    float sum = 0.f;
    for (int q = 0; q < 4; ++q) sum += ss[q][t] * __expf(sm[q][t] - M);
    Mx[t] = M; S[t] = sum;
  }
  __syncthreads();
  const float Mk = Mx[k], Sk = S[k];
  for (int j = 0; j < 256; ++j) {
    const int n = nc * 256 + j;
    const size_t off = ((size_t)b * Nn + n) * Kk + k;
    scores[off] = __expf(scores[off] - Mk) / Sk;
  }
}

// K6c: kfr[b,k,h] = sum_n P[n,k] * hs_rec[n,h]. block=(b, 8-k group), 512 thr
__global__ __launch_bounds__(512) void k6c_kfr(
    const float* __restrict__ scores, const float* __restrict__ hs_rec,
    float* __restrict__ kfr)
{
  const int b = blockIdx.x >> 3, k8 = blockIdx.x & 7;
  const int t = threadIdx.x;
  const int h = t & 127, kq = t >> 7;
  const int k0 = k8 * 8 + kq * 2;
  float a0 = 0.f, a1 = 0.f;
  for (int n = 0; n < Nn; ++n) {
    const float hr = hs_rec[((size_t)b * Nn + n) * Mm + h];
    const float p0 = scores[((size_t)b * Nn + n) * Kk + k0];
    const float p1 = scores[((size_t)b * Nn + n) * Kk + k0 + 1];
    a0 += p0 * hr; a1 += p1 * hr;
  }
  kfr[((size_t)b * Kk + k0) * Mm + h] = a0;
  kfr[((size_t)b * Kk + k0 + 1) * Mm + h] = a1;
}

// ---------------------------------------------------------------------------
// K7: final fused stage, block per b (512 threads)
//   key_rep = sum_k att_l*la_lh + [ (sum_k att_l*kfr) @ kRT + (sum att_l)*kR_b ]
//   grid_rep = sum_g att_r*ra_rh ; pair -> mapL -> fin
// ---------------------------------------------------------------------------
__global__ __launch_bounds__(512) void k7_final(
    const float* __restrict__ attl_part, const float* __restrict__ att_r,
    const float* __restrict__ la_lh, const float* __restrict__ kfr,
    const float* __restrict__ kRT, const float* __restrict__ kR_b,
    const float* __restrict__ ra_rh, const float* __restrict__ lig_rep,
    const float* __restrict__ mapL_w, const float* __restrict__ mapL_b,
    const float* __restrict__ fin_w, const float* __restrict__ fin_b,
    float* __restrict__ out)
{
  const int b = blockIdx.x;
  const int t = threadIdx.x;
  const int h = t & 127, sgrp = t >> 7;
  __shared__ float s_attl[64];
  __shared__ float s_attr[Gg];
  __shared__ float s_pair[260];
  __shared__ float s_u[Mm];
  __shared__ float s_red[4][Mm];
  __shared__ float s5[8];

  if (t < 64) {
    float a = 0.f;
    for (int p = 0; p < 8; ++p) a += attl_part[(b * 8 + p) * 64 + t];
    s_attl[t] = a;
  }
  if (t < Gg) s_attr[t] = att_r[b * Gg + t];
  __syncthreads();

  // key_rep (attention part)
  {
    float acc = 0.f;
    for (int j = 0; j < 16; ++j) {
      const int k = sgrp * 16 + j;
      acc += s_attl[k] * la_lh[((size_t)b * Kk + k) * Mm + h];
    }
    s_red[sgrp][h] = acc;
  }
  __syncthreads();
  if (sgrp == 0) s_pair[h] = s_red[0][h] + s_red[1][h] + s_red[2][h] + s_red[3][h];
  __syncthreads();

  // u = sum_k att_l * kfr
  {
    float acc = 0.f;
    for (int j = 0; j < 16; ++j) {
      const int k = sgrp * 16 + j;
      acc += s_attl[k] * kfr[((size_t)b * Kk + k) * Mm + h];
    }
    s_red[sgrp][h] = acc;
  }
  __syncthreads();
  if (sgrp == 0) s_u[h] = s_red[0][h] + s_red[1][h] + s_red[2][h] + s_red[3][h];
  __syncthreads();

  // kfr2 = u @ kRT + sA * kR_b, added to key_rep
  {
    float acc = 0.f;
    for (int j = 0; j < 32; ++j) {
      const int hp = sgrp * 32 + j;
      acc += s_u[hp] * kRT[(size_t)hp * Mm + h];
    }
    s_red[sgrp][h] = acc;
  }
  __syncthreads();
  if (sgrp == 0) {
    float sA = 0.f;
    for (int k2 = 0; k2 < 64; ++k2) sA += s_attl[k2];
    s_pair[h] += s_red[0][h] + s_red[1][h] + s_red[2][h] + s_red[3][h] + sA * kR_b[h];
  }
  __syncthreads();

  // grid_rep
  {
    float acc = 0.f;
    for (int j = 0; j < 128; ++j) {
      const int g = sgrp * 128 + j;
      acc += s_attr[g] * ra_rh[((size_t)b * Gg + g) * Mm + h];
    }
    s_red[sgrp][h] = acc;
  }
  __syncthreads();
  if (sgrp == 0) s_pair[132 + h] = s_red[0][h] + s_red[1][h] + s_red[2][h] + s_red[3][h];
  if (t < 4) s_pair[128 + t] = lig_rep[b * 4 + t];
  __syncthreads();

  // mapL: 5 outputs over 260 inputs
  const int l = t >> 6, lane = t & 63;
  if (l < 5) {
    float acc = 0.f;
    for (int c = lane; c < 260; c += 64) acc += s_pair[c] * mapL_w[l * 260 + c];
    for (int off = 32; off; off >>= 1) acc += __shfl_xor(acc, off);
    if (lane == 0) s5[l] = acc + mapL_b[l];
  }
  __syncthreads();
  if (t == 0) {
    float o = fin_b[0];
    for (int l2 = 0; l2 < 5; ++l2) o += s5[l2] * fin_w[l2];
    out[b] = o;
  }
}

// ---------------------------------------------------------------------------
extern "C" void kernel_launch(void* const* d_in, const int* in_sizes, int n_in,
                              void* d_out, int out_size, void* d_ws, size_t ws_size,
                              hipStream_t stream) {
  const float* z       = (const float*)d_in[0];
  const float* hs_grid = (const float*)d_in[1];
  const float* hs_key  = (const float*)d_in[2];
  const float* lig_rep = (const float*)d_in[3];
  const float* hs_rec  = (const float*)d_in[4];
  const float* w_Rl    = (const float*)d_in[5];
  const int*   w_mask  = (const int*)d_in[6];
  const float* wra_w = (const float*)d_in[7];  const float* wra_b = (const float*)d_in[8];
  const float* wrh_w = (const float*)d_in[9];  const float* wrh_b = (const float*)d_in[10];
  const float* wla_w = (const float*)d_in[11]; const float* wla_b = (const float*)d_in[12];
  const float* wlh_w = (const float*)d_in[13]; const float* wlh_b = (const float*)d_in[14];
  const float* z1_w  = (const float*)d_in[15];
  const float* wcR_w = (const float*)d_in[17]; const float* wcR_b = (const float*)d_in[18];
  const float* wcl_w = (const float*)d_in[19]; const float* wcl_b = (const float*)d_in[20];
  const float* kR_w  = (const float*)d_in[21]; const float* kR_b  = (const float*)d_in[22];
  const float* mapL_w = (const float*)d_in[23]; const float* mapL_b = (const float*)d_in[24];
  const float* fin_w  = (const float*)d_in[25]; const float* fin_b  = (const float*)d_in[26];
  float* out = (float*)d_out;

  float* w = (float*)d_ws;
  float* wT    = w;                        // 7 * 16384
  float* ra    = wT + 7 * 16384;           // B*G*M
  float* att   = ra + Bb * Gg * Mm;        // B*G*K
  float* laNum = att + Bb * Gg * Kk;       // B*32*K*M
  float* laDen = laNum + Bb * 32 * Kk * Mm;
  float* la    = laDen + Bb * 32 * Kk * Mm;   // B*K*M
  float* attlP = la + Bb * Kk * Mm;        // B*8*64
  float* attrPM = attlP + Bb * 8 * 64;
  float* attrPS = attrPM + Bb * 8 * 64;
  float* att_r = attrPS + Bb * 8 * 64;     // B*G
  float* ra_rh = att_r + Bb * Gg;          // B*G*M
  float* la_lh = ra_rh + Bb * Gg * Mm;     // B*K*M
  float* Rh    = la_lh + Bb * Kk * Mm;     // B*N*M
  float* lh    = Rh + Bb * Nn * Mm;        // B*K*M
  float* scores = lh + Bb * Kk * Mm;       // B*N*K
  float* kfr   = scores + Bb * Nn * Kk;    // B*K*M

  P7 ptrs;
  ptrs.p[0] = wra_w; ptrs.p[1] = wrh_w; ptrs.p[2] = wla_w; ptrs.p[3] = wlh_w;
  ptrs.p[4] = wcR_w; ptrs.p[5] = wcl_w; ptrs.p[6] = kR_w;

  transpose7<<<dim3(4, 4, 7), dim3(32, 8), 0, stream>>>(ptrs, wT);
  k1_stream_z<<<Bb * 32, 1024, 0, stream>>>(z, hs_grid, hs_key, z1_w, ra, att, laNum, laDen);
  k2_reduce_la<<<256, 256, 0, stream>>>(laNum, laDen, la);
  k3_attl<<<Bb * 8, 256, 0, stream>>>(att, attlP);
  k4a_attr_ms<<<Bb * 8, 256, 0, stream>>>(att, attrPM, attrPS);
  k4b_attr<<<Bb * 8, 256, 0, stream>>>(att, attrPM, attrPS, att_r);
  k5_linear2<<<Bb * Nn / 16, 256, 0, stream>>>(hs_rec, wT + 4 * 16384, nullptr, nullptr, wcR_b, nullptr, Rh);
  k5_linear2<<<Bb * Kk / 16, 256, 0, stream>>>(hs_key, wT + 5 * 16384, nullptr, nullptr, wcl_b, nullptr, lh);
  k5_linear2<<<Bb * Gg / 16, 256, 0, stream>>>(ra, wT, hs_grid, wT + 1 * 16384, wra_b, wrh_b, ra_rh);
  k5_linear2<<<Bb * Kk / 16, 256, 0, stream>>>(la, wT + 2 * 16384, hs_key, wT + 3 * 16384, wla_b, wlh_b, la_lh);
  k6a_scores<<<Bb * 64, 256, 0, stream>>>(Rh, lh, w_mask, w_Rl, scores);
  k6b_softmax_n<<<Bb, 256, 0, stream>>>(scores);
  k6c_kfr<<<Bb * 8, 512, 0, stream>>>(scores, hs_rec, kfr);
  k7_final<<<Bb, 512, 0, stream>>>(attlP, att_r, la_lh, kfr, wT + 6 * 16384, kR_b,
                                   ra_rh, lig_rep, mapL_w, mapL_b, fin_w, fin_b, out);
}

// Round 2
// 192.258 us; speedup vs baseline: 1.7249x; 1.7249x over previous
//
#include <hip/hip_runtime.h>

// Problem dims
#define Bb 8
#define Gg 512
#define Kk 64
#define Nn 1024
#define Mm 128

struct P7 { const float* p[7]; };

// ---------------------------------------------------------------------------
// K0: transpose seven 128x128 weight matrices into ws (WT[h][m] = W[m][h])
// ---------------------------------------------------------------------------
__global__ __launch_bounds__(256) void transpose7(P7 ptrs, float* __restrict__ outT) {
  __shared__ float tile[32][33];
  const int mat = blockIdx.z;
  const float* src = ptrs.p[mat];
  float* dst = outT + (size_t)mat * Mm * Mm;
  const int tx = threadIdx.x, ty = threadIdx.y;
  const int xo = blockIdx.x * 32, y0 = blockIdx.y * 32;
  for (int j = ty; j < 32; j += 8) tile[j][tx] = src[(size_t)(y0 + j) * Mm + xo + tx];
  __syncthreads();
  for (int j = ty; j < 32; j += 8) dst[(size_t)(xo + j) * Mm + y0 + tx] = tile[tx][j];
}

// ---------------------------------------------------------------------------
// K1: single pass over z. Computes:
//   ra[b,g,m]   = (sum_k e*hs_key)/(sum_k e)          (finalized per g)
//   att[b,g,k]  = sum_m z*z1w[m]                       (bias dropped: cancels)
//   laNum/laDen partials per g-chunk of 16             (reduced in K2)
// ---------------------------------------------------------------------------
__global__ __launch_bounds__(1024) void k1_stream_z(
    const float* __restrict__ z, const float* __restrict__ hs_grid,
    const float* __restrict__ hs_key, const float* __restrict__ z1w,
    float* __restrict__ raOut, float* __restrict__ attOut,
    float* __restrict__ laNum, float* __restrict__ laDen)
{
  __shared__ __align__(16) float s_hskey[Kk * Mm];    // 32 KB
  __shared__ __align__(16) float s_hsgrid[16 * Mm];   // 8 KB
  __shared__ __align__(16) float s_rn[16 * Mm];       // 8 KB
  __shared__ __align__(16) float s_rd[16 * Mm];       // 8 KB

  const int t = threadIdx.x;
  const int b = blockIdx.x >> 5;
  const int gblk = blockIdx.x & 31;
  const int lane_m = t & 31;
  const int m4 = lane_m << 2;
  const int kgrp = t >> 5;   // 0..31
  const int w = t >> 6;      // wave 0..15

  const float* hkb = hs_key + (size_t)b * Kk * Mm;
  for (int idx = t; idx < Kk * Mm; idx += 1024) s_hskey[idx] = hkb[idx];
  const float* hgb = hs_grid + ((size_t)b * Gg + gblk * 16) * Mm;
  for (int idx = t; idx < 16 * Mm; idx += 1024) s_hsgrid[idx] = hgb[idx];

  const float zw0 = z1w[m4], zw1 = z1w[m4 + 1], zw2 = z1w[m4 + 2], zw3 = z1w[m4 + 3];

  float la_n[2][4], la_d[2][4];
#pragma unroll
  for (int i = 0; i < 2; ++i)
#pragma unroll
    for (int j = 0; j < 4; ++j) { la_n[i][j] = 0.f; la_d[i][j] = 0.f; }

  __syncthreads();

  for (int gl = 0; gl < 16; ++gl) {
    const int g = gblk * 16 + gl;
    const float* zp = z + (((size_t)b * Gg + g) * Kk) * Mm;
    const float4 hg = *reinterpret_cast<const float4*>(s_hsgrid + gl * Mm + m4);
    float rn0 = 0, rn1 = 0, rn2 = 0, rn3 = 0, rd0 = 0, rd1 = 0, rd2 = 0, rd3 = 0;
#pragma unroll
    for (int i = 0; i < 2; ++i) {
      const int k = kgrp * 2 + i;
      const float4 v = *reinterpret_cast<const float4*>(zp + k * Mm + m4);
      const float e0 = __expf(v.x), e1 = __expf(v.y), e2 = __expf(v.z), e3 = __expf(v.w);
      la_n[i][0] += e0 * hg.x; la_n[i][1] += e1 * hg.y; la_n[i][2] += e2 * hg.z; la_n[i][3] += e3 * hg.w;
      la_d[i][0] += e0;        la_d[i][1] += e1;        la_d[i][2] += e2;        la_d[i][3] += e3;
      const float4 hk = *reinterpret_cast<const float4*>(s_hskey + k * Mm + m4);
      rn0 += e0 * hk.x; rn1 += e1 * hk.y; rn2 += e2 * hk.z; rn3 += e3 * hk.w;
      rd0 += e0; rd1 += e1; rd2 += e2; rd3 += e3;
      float ap = v.x * zw0 + v.y * zw1 + v.z * zw2 + v.w * zw3;
      ap += __shfl_xor(ap, 16); ap += __shfl_xor(ap, 8); ap += __shfl_xor(ap, 4);
      ap += __shfl_xor(ap, 2);  ap += __shfl_xor(ap, 1);
      if (lane_m == 0) attOut[((size_t)b * Gg + g) * Kk + k] = ap;
    }
    rn0 += __shfl_xor(rn0, 32); rn1 += __shfl_xor(rn1, 32); rn2 += __shfl_xor(rn2, 32); rn3 += __shfl_xor(rn3, 32);
    rd0 += __shfl_xor(rd0, 32); rd1 += __shfl_xor(rd1, 32); rd2 += __shfl_xor(rd2, 32); rd3 += __shfl_xor(rd3, 32);
    if ((t & 63) < 32) {
      float4 a = make_float4(rn0, rn1, rn2, rn3);
      float4 d = make_float4(rd0, rd1, rd2, rd3);
      *reinterpret_cast<float4*>(s_rn + w * Mm + m4) = a;
      *reinterpret_cast<float4*>(s_rd + w * Mm + m4) = d;
    }
    __syncthreads();
    if (t < Mm) {
      float num = 0.f, den = 0.f;
#pragma unroll
      for (int ww = 0; ww < 16; ++ww) { num += s_rn[ww * Mm + t]; den += s_rd[ww * Mm + t]; }
      raOut[((size_t)b * Gg + g) * Mm + t] = num / den;
    }
    __syncthreads();
  }

  const size_t base = (((size_t)b * 32 + gblk) * Kk) * Mm;
#pragma unroll
  for (int i = 0; i < 2; ++i) {
    const int k = kgrp * 2 + i;
    float4 n4 = make_float4(la_n[i][0], la_n[i][1], la_n[i][2], la_n[i][3]);
    float4 d4 = make_float4(la_d[i][0], la_d[i][1], la_d[i][2], la_d[i][3]);
    *reinterpret_cast<float4*>(laNum + base + k * Mm + m4) = n4;
    *reinterpret_cast<float4*>(laDen + base + k * Mm + m4) = d4;
  }
}

// ---------------------------------------------------------------------------
// K2: la[b,k,m] = (sum_p num_p) / (sum_p den_p)   over 32 g-chunk partials
// ---------------------------------------------------------------------------
__global__ __launch_bounds__(256) void k2_reduce_la(
    const float* __restrict__ laNum, const float* __restrict__ laDen,
    float* __restrict__ la)
{
  const int idx = blockIdx.x * 256 + threadIdx.x;   // B*K*M = 65536
  const int b = idx >> 13;
  const int r = idx & 8191;
  const float* np = laNum + (size_t)b * 32 * 8192 + r;
  const float* dp = laDen + (size_t)b * 32 * 8192 + r;
  float num = 0.f, den = 0.f;
#pragma unroll 8
  for (int p = 0; p < 32; ++p) { num += np[p * 8192]; den += dp[p * 8192]; }
  la[idx] = num / den;
}

// ---------------------------------------------------------------------------
// K3: att_l partials: attl_part[b,p,k] = sum over 64 g's of softmax_k(att)
// ---------------------------------------------------------------------------
__global__ __launch_bounds__(256) void k3_attl(const float* __restrict__ att,
                                               float* __restrict__ attl_part)
{
  const int b = blockIdx.x >> 3, p = blockIdx.x & 7;
  const int t = threadIdx.x;
  const int w = t >> 6, lane = t & 63;
  float acc = 0.f;
  for (int j = 0; j < 16; ++j) {
    const int g = p * 64 + w * 16 + j;
    const float a = att[((size_t)b * Gg + g) * Kk + lane];
    float mx = a;
    for (int off = 32; off; off >>= 1) mx = fmaxf(mx, __shfl_xor(mx, off));
    const float e = __expf(a - mx);
    float s = e;
    for (int off = 32; off; off >>= 1) s += __shfl_xor(s, off);
    acc += e / s;
  }
  __shared__ float sred[4][64];
  sred[w][lane] = acc;
  __syncthreads();
  if (t < 64) attl_part[(b * 8 + p) * 64 + t] = sred[0][t] + sred[1][t] + sred[2][t] + sred[3][t];
}

// ---------------------------------------------------------------------------
// K4a: column (over g) online max/sum partials per (b, gc, k)
// ---------------------------------------------------------------------------
__global__ __launch_bounds__(256) void k4a_attr_ms(const float* __restrict__ att,
                                                   float* __restrict__ pm, float* __restrict__ ps)
{
  const int b = blockIdx.x >> 3, gc = blockIdx.x & 7;
  const int t = threadIdx.x;
  const int k = t & 63, j4 = t >> 6;
  float m = -1e30f, s = 0.f;
  for (int j = 0; j < 16; ++j) {
    const int g = gc * 64 + j4 * 16 + j;
    const float a = att[((size_t)b * Gg + g) * Kk + k];
    if (a > m) { s = s * __expf(m - a) + 1.0f; m = a; }
    else s += __expf(a - m);
  }
  __shared__ float sm[4][64], ss[4][64];
  sm[j4][k] = m; ss[j4][k] = s;
  __syncthreads();
  if (t < 64) {
    float M = sm[0][t];
    for (int q = 1; q < 4; ++q) M = fmaxf(M, sm[q][t]);
    float S = 0.f;
    for (int q = 0; q < 4; ++q) S += ss[q][t] * __expf(sm[q][t] - M);
    pm[(b * 8 + gc) * 64 + t] = M;
    ps[(b * 8 + gc) * 64 + t] = S;
  }
}

// K4b: att_r[b,g] = sum_k exp(a - Mx[k]) / S[k]
__global__ __launch_bounds__(256) void k4b_attr(const float* __restrict__ att,
                                                const float* __restrict__ pm, const float* __restrict__ ps,
                                                float* __restrict__ att_r)
{
  const int b = blockIdx.x >> 3, gc = blockIdx.x & 7;
  const int t = threadIdx.x;
  const int k = t & 63, grp = t >> 6;
  __shared__ float Mx[64], S[64];
  if (t < 64) {
    float M = -1e30f;
    for (int p = 0; p < 8; ++p) M = fmaxf(M, pm[(b * 8 + p) * 64 + t]);
    float s = 0.f;
    for (int p = 0; p < 8; ++p) s += ps[(b * 8 + p) * 64 + t] * __expf(pm[(b * 8 + p) * 64 + t] - M);
    Mx[t] = M; S[t] = s;
  }
  __syncthreads();
  const float Mk = Mx[k], Sk = S[k];
  for (int j = 0; j < 16; ++j) {
    const int g = gc * 64 + grp * 16 + j;
    float p = __expf(att[((size_t)b * Gg + g) * Kk + k] - Mk) / Sk;
    for (int off = 32; off; off >>= 1) p += __shfl_xor(p, off);
    if (k == 0) att_r[b * Gg + g] = p;
  }
}

// ---------------------------------------------------------------------------
// K5: generic linear: out[r,m] = in1[r,:]@W1T (+ in2[r,:]@W2T) + b1 (+ b2)
// ---------------------------------------------------------------------------
__global__ __launch_bounds__(256) void k5_linear2(
    const float* __restrict__ in1, const float* __restrict__ W1T,
    const float* __restrict__ in2, const float* __restrict__ W2T,
    const float* __restrict__ b1, const float* __restrict__ b2,
    float* __restrict__ out)
{
  __shared__ float s1[16][Mm];
  __shared__ float s2[16][Mm];
  __shared__ float sacc[16][Mm];
  const int r0 = blockIdx.x * 16;
  const int t = threadIdx.x;
  const int m = t & 127, hh = t >> 7;
  for (int idx = t; idx < 16 * Mm; idx += 256) s1[idx >> 7][idx & 127] = in1[(size_t)r0 * Mm + idx];
  if (in2) for (int idx = t; idx < 16 * Mm; idx += 256) s2[idx >> 7][idx & 127] = in2[(size_t)r0 * Mm + idx];
  __syncthreads();
  float acc[16];
#pragma unroll
  for (int r = 0; r < 16; ++r) acc[r] = 0.f;
  const int h0 = hh * 64;
  if (in2) {
    for (int h = h0; h < h0 + 64; ++h) {
      const float w1 = W1T[(size_t)h * Mm + m];
      const float w2 = W2T[(size_t)h * Mm + m];
#pragma unroll
      for (int r = 0; r < 16; ++r) acc[r] += s1[r][h] * w1 + s2[r][h] * w2;
    }
  } else {
    for (int h = h0; h < h0 + 64; ++h) {
      const float w1 = W1T[(size_t)h * Mm + m];
#pragma unroll
      for (int r = 0; r < 16; ++r) acc[r] += s1[r][h] * w1;
    }
  }
  if (hh == 1) {
#pragma unroll
    for (int r = 0; r < 16; ++r) sacc[r][m] = acc[r];
  }
  __syncthreads();
  if (hh == 0) {
    const float bias = b1[m] + (b2 ? b2[m] : 0.f);
#pragma unroll
    for (int r = 0; r < 16; ++r) out[(size_t)(r0 + r) * Mm + m] = acc[r] + sacc[r][m] + bias;
  }
}

// ---------------------------------------------------------------------------
// K6a: scores[b,n,k] = mask ? w_Rl * dot(Rh[n,:], lh[k,:]) : -1e10
// Also emits per-16n-tile online softmax partials pm/ps[b, ntile, k].
// ---------------------------------------------------------------------------
__global__ __launch_bounds__(256) void k6a_scores(
    const float* __restrict__ Rh, const float* __restrict__ lh,
    const int* __restrict__ mask, const float* __restrict__ wRl,
    float* __restrict__ scores, float* __restrict__ pmT, float* __restrict__ psT)
{
  __shared__ float s_rh[16][Mm];
  __shared__ float s_lh[64][Mm + 1];
  __shared__ float s_acc[4][16][64];
  __shared__ float s_m[4][64];
  __shared__ float s_s[4][64];
  const int b = blockIdx.x >> 6;
  const int ntile = blockIdx.x & 63;
  const int n0 = ntile * 16;
  const int t = threadIdx.x;
  const int k = t & 63, hs = t >> 6;
  for (int idx = t; idx < 16 * Mm; idx += 256)
    s_rh[idx >> 7][idx & 127] = Rh[((size_t)b * Nn + n0) * Mm + idx];
  for (int idx = t; idx < 64 * Mm; idx += 256)
    s_lh[idx >> 7][idx & 127] = lh[(size_t)b * Kk * Mm + idx];
  __syncthreads();
  float acc[16];
#pragma unroll
  for (int r = 0; r < 16; ++r) acc[r] = 0.f;
  for (int h = hs * 32; h < hs * 32 + 32; ++h) {
    const float lv = s_lh[k][h];
#pragma unroll
    for (int r = 0; r < 16; ++r) acc[r] += s_rh[r][h] * lv;
  }
#pragma unroll
  for (int r = 0; r < 16; ++r) s_acc[hs][r][k] = acc[r];
  __syncthreads();
  const float wv = wRl[0];
  const bool msk = (mask[b * Kk + k] == 0);   // k == t&63 == idx&63 for all q
  float m = -3.0e38f, ssum = 0.f;
  for (int q = 0; q < 4; ++q) {
    const int idx = q * 256 + t;
    const int r = idx >> 6, kk = idx & 63;
    float v = s_acc[0][r][kk] + s_acc[1][r][kk] + s_acc[2][r][kk] + s_acc[3][r][kk];
    v = msk ? -1e10f : wv * v;
    scores[((size_t)b * Nn + n0 + r) * Kk + kk] = v;
    if (v > m) { ssum = ssum * __expf(m - v) + 1.0f; m = v; }
    else ssum += __expf(v - m);
  }
  s_m[hs][k] = m; s_s[hs][k] = ssum;
  __syncthreads();
  if (t < 64) {
    float M = fmaxf(fmaxf(s_m[0][t], s_m[1][t]), fmaxf(s_m[2][t], s_m[3][t]));
    float S = 0.f;
#pragma unroll
    for (int q = 0; q < 4; ++q) S += s_s[q][t] * __expf(s_m[q][t] - M);
    pmT[((size_t)b * 64 + ntile) * 64 + t] = M;
    psT[((size_t)b * 64 + ntile) * 64 + t] = S;
  }
}

// K6b2: finalize per-(b,k) softmax stats: M and 1/S over the 64 n-tiles.
__global__ __launch_bounds__(512) void k6b2_fin(
    const float* __restrict__ pmT, const float* __restrict__ psT,
    float* __restrict__ Mfin, float* __restrict__ Sinv)
{
  const int t = threadIdx.x;      // = b*64 + k
  const int b = t >> 6, k = t & 63;
  float M = -3.0e38f;
#pragma unroll 8
  for (int nt = 0; nt < 64; ++nt) M = fmaxf(M, pmT[((size_t)b * 64 + nt) * 64 + k]);
  float S = 0.f;
#pragma unroll 8
  for (int nt = 0; nt < 64; ++nt)
    S += psT[((size_t)b * 64 + nt) * 64 + k] * __expf(pmT[((size_t)b * 64 + nt) * 64 + k] - M);
  Mfin[t] = M;
  Sinv[t] = 1.0f / S;
}

// ---------------------------------------------------------------------------
// K6c: partial kfr over 256-n chunks; P computed on the fly into LDS.
//   kfrP[b,ns,k,h] = sum_{n in chunk} exp(scores-M)/S * hs_rec[n,h]
// grid = B*8*4; block 512: h = t&127, kq = t>>7 (2 k's each)
// ---------------------------------------------------------------------------
__global__ __launch_bounds__(512) void k6c_part(
    const float* __restrict__ scores, const float* __restrict__ hs_rec,
    const float* __restrict__ Mfin, const float* __restrict__ Sinv,
    float* __restrict__ kfrP)
{
  __shared__ float sP[256][8];   // 8 KB
  const int b = blockIdx.x >> 5;
  const int k8 = (blockIdx.x >> 2) & 7;
  const int ns = blockIdx.x & 3;
  const int t = threadIdx.x;
  const int h = t & 127, kq = t >> 7;
  const int n0 = ns * 256;
  {
    const float* sc = scores + ((size_t)b * Nn + n0) * Kk + k8 * 8;
    for (int idx = t; idx < 2048; idx += 512) {
      const int n = idx >> 3, kk = idx & 7;
      const int kg = k8 * 8 + kk;
      sP[n][kk] = __expf(sc[(size_t)n * Kk + kk] - Mfin[b * 64 + kg]) * Sinv[b * 64 + kg];
    }
  }
  __syncthreads();
  const int kk0 = kq * 2;
  float a0 = 0.f, a1 = 0.f;
  const float* hr = hs_rec + ((size_t)b * Nn + n0) * Mm + h;
  for (int n = 0; n < 256; ++n) {
    const float hv = hr[(size_t)n * Mm];
    a0 += sP[n][kk0] * hv;
    a1 += sP[n][kk0 + 1] * hv;
  }
  const int k0 = k8 * 8 + kk0;
  kfrP[(((size_t)b * 4 + ns) * Kk + k0) * Mm + h] = a0;
  kfrP[(((size_t)b * 4 + ns) * Kk + k0 + 1) * Mm + h] = a1;
}

// ---------------------------------------------------------------------------
// K7: final fused stage, block per b (512 threads)
// ---------------------------------------------------------------------------
__global__ __launch_bounds__(512) void k7_final(
    const float* __restrict__ attl_part, const float* __restrict__ att_r,
    const float* __restrict__ la_lh, const float* __restrict__ kfrP,
    const float* __restrict__ kRT, const float* __restrict__ kR_b,
    const float* __restrict__ ra_rh, const float* __restrict__ lig_rep,
    const float* __restrict__ mapL_w, const float* __restrict__ mapL_b,
    const float* __restrict__ fin_w, const float* __restrict__ fin_b,
    float* __restrict__ out)
{
  const int b = blockIdx.x;
  const int t = threadIdx.x;
  const int h = t & 127, sgrp = t >> 7;
  __shared__ float s_attl[64];
  __shared__ float s_attr[Gg];
  __shared__ float s_pair[260];
  __shared__ float s_u[Mm];
  __shared__ float s_red[4][Mm];
  __shared__ float s5[8];

  if (t < 64) {
    float a = 0.f;
    for (int p = 0; p < 8; ++p) a += attl_part[(b * 8 + p) * 64 + t];
    s_attl[t] = a;
  }
  if (t < Gg) s_attr[t] = att_r[b * Gg + t];
  __syncthreads();

  // key_rep (attention part)
  {
    float acc = 0.f;
    for (int j = 0; j < 16; ++j) {
      const int k = sgrp * 16 + j;
      acc += s_attl[k] * la_lh[((size_t)b * Kk + k) * Mm + h];
    }
    s_red[sgrp][h] = acc;
  }
  __syncthreads();
  if (sgrp == 0) s_pair[h] = s_red[0][h] + s_red[1][h] + s_red[2][h] + s_red[3][h];
  __syncthreads();

  // u = sum_{ns,k} att_l[k] * kfrP[b,ns,k,h]
  {
    float acc = 0.f;
    for (int j = 0; j < 64; ++j) {
      const int row = sgrp * 64 + j;          // row = ns*64 + k
      acc += s_attl[row & 63] * kfrP[((size_t)b * 256 + row) * Mm + h];
    }
    s_red[sgrp][h] = acc;
  }
  __syncthreads();
  if (sgrp == 0) s_u[h] = s_red[0][h] + s_red[1][h] + s_red[2][h] + s_red[3][h];
  __syncthreads();

  // kfr2 = u @ kRT + sA * kR_b, added to key_rep
  {
    float acc = 0.f;
    for (int j = 0; j < 32; ++j) {
      const int hp = sgrp * 32 + j;
      acc += s_u[hp] * kRT[(size_t)hp * Mm + h];
    }
    s_red[sgrp][h] = acc;
  }
  __syncthreads();
  if (sgrp == 0) {
    float sA = 0.f;
    for (int k2 = 0; k2 < 64; ++k2) sA += s_attl[k2];
    s_pair[h] += s_red[0][h] + s_red[1][h] + s_red[2][h] + s_red[3][h] + sA * kR_b[h];
  }
  __syncthreads();

  // grid_rep
  {
    float acc = 0.f;
    for (int j = 0; j < 128; ++j) {
      const int g = sgrp * 128 + j;
      acc += s_attr[g] * ra_rh[((size_t)b * Gg + g) * Mm + h];
    }
    s_red[sgrp][h] = acc;
  }
  __syncthreads();
  if (sgrp == 0) s_pair[132 + h] = s_red[0][h] + s_red[1][h] + s_red[2][h] + s_red[3][h];
  if (t < 4) s_pair[128 + t] = lig_rep[b * 4 + t];
  __syncthreads();

  // mapL: 5 outputs over 260 inputs
  const int l = t >> 6, lane = t & 63;
  if (l < 5) {
    float acc = 0.f;
    for (int c = lane; c < 260; c += 64) acc += s_pair[c] * mapL_w[l * 260 + c];
    for (int off = 32; off; off >>= 1) acc += __shfl_xor(acc, off);
    if (lane == 0) s5[l] = acc + mapL_b[l];
  }
  __syncthreads();
  if (t == 0) {
    float o = fin_b[0];
    for (int l2 = 0; l2 < 5; ++l2) o += s5[l2] * fin_w[l2];
    out[b] = o;
  }
}

// ---------------------------------------------------------------------------
extern "C" void kernel_launch(void* const* d_in, const int* in_sizes, int n_in,
                              void* d_out, int out_size, void* d_ws, size_t ws_size,
                              hipStream_t stream) {
  const float* z       = (const float*)d_in[0];
  const float* hs_grid = (const float*)d_in[1];
  const float* hs_key  = (const float*)d_in[2];
  const float* lig_rep = (const float*)d_in[3];
  const float* hs_rec  = (const float*)d_in[4];
  const float* w_Rl    = (const float*)d_in[5];
  const int*   w_mask  = (const int*)d_in[6];
  const float* wra_w = (const float*)d_in[7];  const float* wra_b = (const float*)d_in[8];
  const float* wrh_w = (const float*)d_in[9];  const float* wrh_b = (const float*)d_in[10];
  const float* wla_w = (const float*)d_in[11]; const float* wla_b = (const float*)d_in[12];
  const float* wlh_w = (const float*)d_in[13]; const float* wlh_b = (const float*)d_in[14];
  const float* z1_w  = (const float*)d_in[15];
  const float* wcR_w = (const float*)d_in[17]; const float* wcR_b = (const float*)d_in[18];
  const float* wcl_w = (const float*)d_in[19]; const float* wcl_b = (const float*)d_in[20];
  const float* kR_w  = (const float*)d_in[21]; const float* kR_b  = (const float*)d_in[22];
  const float* mapL_w = (const float*)d_in[23]; const float* mapL_b = (const float*)d_in[24];
  const float* fin_w  = (const float*)d_in[25]; const float* fin_b  = (const float*)d_in[26];
  float* out = (float*)d_out;

  float* w = (float*)d_ws;
  float* wT    = w;                        // 7 * 16384
  float* ra    = wT + 7 * 16384;           // B*G*M
  float* att   = ra + Bb * Gg * Mm;        // B*G*K
  float* laNum = att + Bb * Gg * Kk;       // B*32*K*M (free after k2)
  float* laDen = laNum + Bb * 32 * Kk * Mm; // (free after k2)
  float* la    = laDen + Bb * 32 * Kk * Mm;   // B*K*M
  float* attlP = la + Bb * Kk * Mm;        // B*8*64
  float* attrPM = attlP + Bb * 8 * 64;
  float* attrPS = attrPM + Bb * 8 * 64;
  float* att_r = attrPS + Bb * 8 * 64;     // B*G
  float* ra_rh = att_r + Bb * Gg;          // B*G*M
  float* la_lh = ra_rh + Bb * Gg * Mm;     // B*K*M
  float* Rh    = la_lh + Bb * Kk * Mm;     // B*N*M
  float* lh    = Rh + Bb * Nn * Mm;        // B*K*M
  float* scores = lh + Bb * Kk * Mm;       // B*N*K

  // aliases into laNum/laDen (dead after k2, reused by k6*)
  float* pmT  = laNum;                     // B*64*64 = 32768
  float* psT  = laNum + 32768;             // 32768
  float* Mfin = laNum + 65536;             // 512
  float* Sinv = laNum + 66048;             // 512
  float* kfrP = laDen;                     // B*4*K*M = 262144

  P7 ptrs;
  ptrs.p[0] = wra_w; ptrs.p[1] = wrh_w; ptrs.p[2] = wla_w; ptrs.p[3] = wlh_w;
  ptrs.p[4] = wcR_w; ptrs.p[5] = wcl_w; ptrs.p[6] = kR_w;

  transpose7<<<dim3(4, 4, 7), dim3(32, 8), 0, stream>>>(ptrs, wT);
  k1_stream_z<<<Bb * 32, 1024, 0, stream>>>(z, hs_grid, hs_key, z1_w, ra, att, laNum, laDen);
  k2_reduce_la<<<256, 256, 0, stream>>>(laNum, laDen, la);
  k3_attl<<<Bb * 8, 256, 0, stream>>>(att, attlP);
  k4a_attr_ms<<<Bb * 8, 256, 0, stream>>>(att, attrPM, attrPS);
  k4b_attr<<<Bb * 8, 256, 0, stream>>>(att, attrPM, attrPS, att_r);
  k5_linear2<<<Bb * Nn / 16, 256, 0, stream>>>(hs_rec, wT + 4 * 16384, nullptr, nullptr, wcR_b, nullptr, Rh);
  k5_linear2<<<Bb * Kk / 16, 256, 0, stream>>>(hs_key, wT + 5 * 16384, nullptr, nullptr, wcl_b, nullptr, lh);
  k5_linear2<<<Bb * Gg / 16, 256, 0, stream>>>(ra, wT, hs_grid, wT + 1 * 16384, wra_b, wrh_b, ra_rh);
  k5_linear2<<<Bb * Kk / 16, 256, 0, stream>>>(la, wT + 2 * 16384, hs_key, wT + 3 * 16384, wla_b, wlh_b, la_lh);
  k6a_scores<<<Bb * 64, 256, 0, stream>>>(Rh, lh, w_mask, w_Rl, scores, pmT, psT);
  k6b2_fin<<<1, 512, 0, stream>>>(pmT, psT, Mfin, Sinv);
  k6c_part<<<Bb * 8 * 4, 512, 0, stream>>>(scores, hs_rec, Mfin, Sinv, kfrP);
  k7_final<<<Bb, 512, 0, stream>>>(attlP, att_r, la_lh, kfrP, wT + 6 * 16384, kR_b,
                                   ra_rh, lig_rep, mapL_w, mapL_b, fin_w, fin_b, out);
}

// Round 3
// 99.757 us; speedup vs baseline: 3.3244x; 1.9273x over previous
//
#include <hip/hip_runtime.h>

// Problem dims
#define Bb 8
#define Gg 512
#define Kk 64
#define Nn 1024
#define Mm 128
#define KM (Kk * Mm)      // 8192
#define GPB 8             // g per block in k1
#define NCH (Gg / GPB)    // 64 partial chunks

struct P7 { const float* p[7]; };

// ===========================================================================
// KA: k1 stream-z (blocks 0..511) + 7x weight transpose (blocks 512..623)
// ===========================================================================
__global__ __launch_bounds__(1024) void kA(
    const float* __restrict__ z, const float* __restrict__ hs_grid,
    const float* __restrict__ hs_key, const float* __restrict__ z1w,
    P7 ptrs, float* __restrict__ wT,
    float* __restrict__ raOut, float* __restrict__ attOut,
    float* __restrict__ laNum, float* __restrict__ laDen)
{
  __shared__ __align__(16) float smem[17408];   // 68 KB
  const int bid = blockIdx.x;
  const int t = threadIdx.x;

  if (bid >= Bb * NCH) {
    // ---- weight transpose: 112 blocks, 32x32 tiles, 1024 threads ----
    float* tile = smem;                          // 32*33
    const int r = bid - Bb * NCH;
    const int mat = r >> 4, tl = r & 15;
    const int xo = (tl & 3) * 32, y0 = (tl >> 2) * 32;
    const int tx = t & 31, ty = t >> 5;          // 32 x 32
    const float* src = ptrs.p[mat];
    float* dst = wT + (size_t)mat * Mm * Mm;
    tile[ty * 33 + tx] = src[(size_t)(y0 + ty) * Mm + xo + tx];
    __syncthreads();
    dst[(size_t)(xo + ty) * Mm + y0 + tx] = tile[tx * 33 + ty];
    return;
  }

  // ---- k1: 8 g per block ----
  float* s_hskey  = smem;            // 8192
  float* s_hsgrid = smem + 8192;     // 1024
  float* s_rn     = smem + 9216;     // 2 x 2048 (double buffered)
  float* s_rd     = smem + 13312;    // 2 x 2048

  const int b = bid >> 6;
  const int gblk = bid & 63;
  const int lane_m = t & 31;
  const int m4 = lane_m << 2;
  const int kgrp = t >> 5;           // 0..31
  const int wv = t >> 6;             // 0..15

  const float* hkb = hs_key + (size_t)b * KM;
  for (int idx = t; idx < KM; idx += 1024) s_hskey[idx] = hkb[idx];
  const float* hgb = hs_grid + ((size_t)b * Gg + gblk * GPB) * Mm;
  for (int idx = t; idx < GPB * Mm; idx += 1024) s_hsgrid[idx] = hgb[idx];

  const float zw0 = z1w[m4], zw1 = z1w[m4 + 1], zw2 = z1w[m4 + 2], zw3 = z1w[m4 + 3];

  float la_n[2][4], la_d[2][4];
#pragma unroll
  for (int i = 0; i < 2; ++i)
#pragma unroll
    for (int j = 0; j < 4; ++j) { la_n[i][j] = 0.f; la_d[i][j] = 0.f; }

  const float* zb = z + ((size_t)b * Gg + gblk * GPB) * (size_t)Mm * Kk;
  const int ofs0 = (kgrp * 2) * Mm + m4;
  const int ofs1 = ofs0 + Mm;
  float4 c0 = *reinterpret_cast<const float4*>(zb + ofs0);
  float4 c1 = *reinterpret_cast<const float4*>(zb + ofs1);

  __syncthreads();   // staging ready

  for (int gl = 0; gl < GPB; ++gl) {
    float4 n0 = c0, n1 = c1;
    if (gl < GPB - 1) {
      n0 = *reinterpret_cast<const float4*>(zb + (size_t)(gl + 1) * KM + ofs0);
      n1 = *reinterpret_cast<const float4*>(zb + (size_t)(gl + 1) * KM + ofs1);
    }
    const int g = gblk * GPB + gl;
    const float4 hg = *reinterpret_cast<const float4*>(s_hsgrid + gl * Mm + m4);
    float rn0 = 0, rn1 = 0, rn2 = 0, rn3 = 0, rd0 = 0, rd1 = 0, rd2 = 0, rd3 = 0;
#pragma unroll
    for (int i = 0; i < 2; ++i) {
      const float4 v = (i == 0) ? c0 : c1;
      const int k = kgrp * 2 + i;
      const float e0 = __expf(v.x), e1 = __expf(v.y), e2 = __expf(v.z), e3 = __expf(v.w);
      la_n[i][0] += e0 * hg.x; la_n[i][1] += e1 * hg.y; la_n[i][2] += e2 * hg.z; la_n[i][3] += e3 * hg.w;
      la_d[i][0] += e0;        la_d[i][1] += e1;        la_d[i][2] += e2;        la_d[i][3] += e3;
      const float4 hk = *reinterpret_cast<const float4*>(s_hskey + k * Mm + m4);
      rn0 += e0 * hk.x; rn1 += e1 * hk.y; rn2 += e2 * hk.z; rn3 += e3 * hk.w;
      rd0 += e0; rd1 += e1; rd2 += e2; rd3 += e3;
      float ap = v.x * zw0 + v.y * zw1 + v.z * zw2 + v.w * zw3;
      ap += __shfl_xor(ap, 16); ap += __shfl_xor(ap, 8); ap += __shfl_xor(ap, 4);
      ap += __shfl_xor(ap, 2);  ap += __shfl_xor(ap, 1);
      if (lane_m == 0) attOut[((size_t)b * Gg + g) * Kk + k] = ap;
    }
    // combine the two kgrps within each wave
    rn0 += __shfl_xor(rn0, 32); rn1 += __shfl_xor(rn1, 32); rn2 += __shfl_xor(rn2, 32); rn3 += __shfl_xor(rn3, 32);
    rd0 += __shfl_xor(rd0, 32); rd1 += __shfl_xor(rd1, 32); rd2 += __shfl_xor(rd2, 32); rd3 += __shfl_xor(rd3, 32);
    float* rnB = s_rn + (gl & 1) * 2048;
    float* rdB = s_rd + (gl & 1) * 2048;
    if ((t & 63) < 32) {
      *reinterpret_cast<float4*>(rnB + wv * Mm + m4) = make_float4(rn0, rn1, rn2, rn3);
      *reinterpret_cast<float4*>(rdB + wv * Mm + m4) = make_float4(rd0, rd1, rd2, rd3);
    }
    __syncthreads();
    if (t < Mm) {
      float num = 0.f, den = 0.f;
#pragma unroll
      for (int ww = 0; ww < 16; ++ww) { num += rnB[ww * Mm + t]; den += rdB[ww * Mm + t]; }
      raOut[((size_t)b * Gg + g) * Mm + t] = num / den;
    }
    c0 = n0; c1 = n1;
  }

  const size_t base = ((size_t)(b * NCH + gblk)) * KM;
#pragma unroll
  for (int i = 0; i < 2; ++i) {
    const int k = kgrp * 2 + i;
    *reinterpret_cast<float4*>(laNum + base + k * Mm + m4) =
        make_float4(la_n[i][0], la_n[i][1], la_n[i][2], la_n[i][3]);
    *reinterpret_cast<float4*>(laDen + base + k * Mm + m4) =
        make_float4(la_d[i][0], la_d[i][1], la_d[i][2], la_d[i][3]);
  }
}

// ===========================================================================
// Shared device helper: linear over 16 rows (256 threads)
// ===========================================================================
__device__ __forceinline__ void lin2_body(
    int r0, const float* __restrict__ in1, const float* __restrict__ W1T,
    const float* __restrict__ in2, const float* __restrict__ W2T,
    const float* __restrict__ b1, const float* __restrict__ b2,
    float* __restrict__ out, float* smem)
{
  float* s1 = smem;            // 2048
  float* s2 = smem + 2048;     // 2048
  float* sacc = smem + 4096;   // 2048
  const int t = threadIdx.x;
  const int m = t & 127, hh = t >> 7;
  for (int idx = t; idx < 2048; idx += 256) s1[idx] = in1[(size_t)r0 * Mm + idx];
  if (in2) for (int idx = t; idx < 2048; idx += 256) s2[idx] = in2[(size_t)r0 * Mm + idx];
  __syncthreads();
  float acc[16];
#pragma unroll
  for (int r = 0; r < 16; ++r) acc[r] = 0.f;
  const int h0 = hh * 64;
  if (in2) {
    for (int h = h0; h < h0 + 64; ++h) {
      const float w1 = W1T[(size_t)h * Mm + m];
      const float w2 = W2T[(size_t)h * Mm + m];
#pragma unroll
      for (int r = 0; r < 16; ++r) acc[r] += s1[r * Mm + h] * w1 + s2[r * Mm + h] * w2;
    }
  } else {
    for (int h = h0; h < h0 + 64; ++h) {
      const float w1 = W1T[(size_t)h * Mm + m];
#pragma unroll
      for (int r = 0; r < 16; ++r) acc[r] += s1[r * Mm + h] * w1;
    }
  }
  if (hh == 1) {
#pragma unroll
    for (int r = 0; r < 16; ++r) sacc[r * Mm + m] = acc[r];
  }
  __syncthreads();
  if (hh == 0) {
    const float bias = b1[m] + (b2 ? b2[m] : 0.f);
#pragma unroll
    for (int r = 0; r < 16; ++r) out[(size_t)(r0 + r) * Mm + m] = acc[r] + sacc[r * Mm + m] + bias;
  }
}

// ===========================================================================
// KB: [0,256) la-reduce | [256,320) att_l | [320,384) att_r partials |
//     [384,896) Rh linear | [896,928) lh linear          (256 threads)
// ===========================================================================
__global__ __launch_bounds__(256) void kB(
    const float* __restrict__ laNum, const float* __restrict__ laDen, float* __restrict__ la,
    const float* __restrict__ att, float* __restrict__ attlP,
    float* __restrict__ attrPM, float* __restrict__ attrPS,
    const float* __restrict__ hs_rec, const float* __restrict__ hs_key,
    const float* __restrict__ wT, const float* __restrict__ wcR_b, const float* __restrict__ wcl_b,
    float* __restrict__ Rh, float* __restrict__ lh)
{
  __shared__ __align__(16) float smem[6144];   // 24 KB
  const int bid = blockIdx.x;
  const int t = threadIdx.x;

  if (bid < 256) {
    // ---- k2: la = sum(num)/sum(den) over 64 chunks ----
    const int idx = bid * 256 + t;
    const int b = idx >> 13, r = idx & 8191;
    const float* np = laNum + (size_t)b * NCH * KM + r;
    const float* dp = laDen + (size_t)b * NCH * KM + r;
    float num = 0.f, den = 0.f;
#pragma unroll 8
    for (int p = 0; p < NCH; ++p) { num += np[(size_t)p * KM]; den += dp[(size_t)p * KM]; }
    la[idx] = num / den;
  } else if (bid < 320) {
    // ---- k3: att_l partials ----
    const int blk = bid - 256;
    const int b = blk >> 3, p = blk & 7;
    const int w = t >> 6, lane = t & 63;
    float acc = 0.f;
    for (int j = 0; j < 16; ++j) {
      const int g = p * 64 + w * 16 + j;
      const float a = att[((size_t)b * Gg + g) * Kk + lane];
      float mx = a;
      for (int off = 32; off; off >>= 1) mx = fmaxf(mx, __shfl_xor(mx, off));
      const float e = __expf(a - mx);
      float s = e;
      for (int off = 32; off; off >>= 1) s += __shfl_xor(s, off);
      acc += e / s;
    }
    float* sred = smem;
    sred[w * 64 + lane] = acc;
    __syncthreads();
    if (t < 64) attlP[(b * 8 + p) * 64 + t] = sred[t] + sred[64 + t] + sred[128 + t] + sred[192 + t];
  } else if (bid < 384) {
    // ---- k4a: att_r online max/sum partials ----
    const int blk = bid - 320;
    const int b = blk >> 3, gc = blk & 7;
    const int k = t & 63, j4 = t >> 6;
    float m = -1e30f, s = 0.f;
    for (int j = 0; j < 16; ++j) {
      const int g = gc * 64 + j4 * 16 + j;
      const float a = att[((size_t)b * Gg + g) * Kk + k];
      if (a > m) { s = s * __expf(m - a) + 1.0f; m = a; }
      else s += __expf(a - m);
    }
    float* sm = smem;          // 256
    float* ss = smem + 256;    // 256
    sm[j4 * 64 + k] = m; ss[j4 * 64 + k] = s;
    __syncthreads();
    if (t < 64) {
      float M = sm[t];
      for (int q = 1; q < 4; ++q) M = fmaxf(M, sm[q * 64 + t]);
      float S = 0.f;
      for (int q = 0; q < 4; ++q) S += ss[q * 64 + t] * __expf(sm[q * 64 + t] - M);
      attrPM[(b * 8 + gc) * 64 + t] = M;
      attrPS[(b * 8 + gc) * 64 + t] = S;
    }
  } else if (bid < 896) {
    lin2_body((bid - 384) * 16, hs_rec, wT + 4 * 16384, nullptr, nullptr, wcR_b, nullptr, Rh, smem);
  } else {
    lin2_body((bid - 896) * 16, hs_key, wT + 5 * 16384, nullptr, nullptr, wcl_b, nullptr, lh, smem);
  }
}

// ===========================================================================
// KC: [0,64) att_r final | [64,320) ra_rh | [320,352) la_lh |
//     [352,864) scores + softmax partials                  (256 threads)
// ===========================================================================
__global__ __launch_bounds__(256) void kC(
    const float* __restrict__ att, const float* __restrict__ attrPM, const float* __restrict__ attrPS,
    float* __restrict__ att_r,
    const float* __restrict__ ra, const float* __restrict__ hs_grid,
    const float* __restrict__ la, const float* __restrict__ hs_key,
    const float* __restrict__ wT,
    const float* __restrict__ wra_b, const float* __restrict__ wrh_b,
    const float* __restrict__ wla_b, const float* __restrict__ wlh_b,
    float* __restrict__ ra_rh, float* __restrict__ la_lh,
    const float* __restrict__ Rh, const float* __restrict__ lh,
    const int* __restrict__ mask, const float* __restrict__ wRl,
    float* __restrict__ scores, float* __restrict__ pmT, float* __restrict__ psT)
{
  __shared__ __align__(16) float smem[14912];   // 58.25 KB
  const int bid = blockIdx.x;
  const int t = threadIdx.x;

  if (bid < 64) {
    // ---- k4b: att_r final ----
    const int b = bid >> 3, gc = bid & 7;
    const int k = t & 63, grp = t >> 6;
    float* Mx = smem;        // 64
    float* S = smem + 64;    // 64
    if (t < 64) {
      float M = -1e30f;
      for (int p = 0; p < 8; ++p) M = fmaxf(M, attrPM[(b * 8 + p) * 64 + t]);
      float s = 0.f;
      for (int p = 0; p < 8; ++p) s += attrPS[(b * 8 + p) * 64 + t] * __expf(attrPM[(b * 8 + p) * 64 + t] - M);
      Mx[t] = M; S[t] = s;
    }
    __syncthreads();
    const float Mk = Mx[k], Sk = S[k];
    for (int j = 0; j < 16; ++j) {
      const int g = gc * 64 + grp * 16 + j;
      float p = __expf(att[((size_t)b * Gg + g) * Kk + k] - Mk) / Sk;
      for (int off = 32; off; off >>= 1) p += __shfl_xor(p, off);
      if (k == 0) att_r[b * Gg + g] = p;
    }
  } else if (bid < 320) {
    lin2_body((bid - 64) * 16, ra, wT, hs_grid, wT + 16384, wra_b, wrh_b, ra_rh, smem);
  } else if (bid < 352) {
    lin2_body((bid - 320) * 16, la, wT + 2 * 16384, hs_key, wT + 3 * 16384, wla_b, wlh_b, la_lh, smem);
  } else {
    // ---- k6a: scores + per-tile softmax partials ----
    const int vb = bid - 352;
    const int b = vb >> 6, ntile = vb & 63;
    const int n0 = ntile * 16;
    const int k = t & 63, hs = t >> 6;
    float* s_rh  = smem;                 // 2048
    float* s_lh  = smem + 2048;          // 64*129 = 8256
    float* s_acc = smem + 10304;         // 4096
    float* s_m   = smem + 14400;         // 256
    float* s_s   = smem + 14656;         // 256
    for (int idx = t; idx < 2048; idx += 256)
      s_rh[idx] = Rh[((size_t)b * Nn + n0) * Mm + idx];
    for (int idx = t; idx < 8192; idx += 256)
      s_lh[(idx >> 7) * 129 + (idx & 127)] = lh[(size_t)b * Kk * Mm + idx];
    __syncthreads();
    float acc[16];
#pragma unroll
    for (int r = 0; r < 16; ++r) acc[r] = 0.f;
    for (int h = hs * 32; h < hs * 32 + 32; ++h) {
      const float lv = s_lh[k * 129 + h];
#pragma unroll
      for (int r = 0; r < 16; ++r) acc[r] += s_rh[r * Mm + h] * lv;
    }
#pragma unroll
    for (int r = 0; r < 16; ++r) s_acc[(hs * 16 + r) * 64 + k] = acc[r];
    __syncthreads();
    const float wv = wRl[0];
    const bool msk = (mask[b * Kk + k] == 0);
    float m = -3.0e38f, ssum = 0.f;
    for (int q = 0; q < 4; ++q) {
      const int idx = q * 256 + t;
      const int r = idx >> 6, kk = idx & 63;
      float v = s_acc[r * 64 + kk] + s_acc[(16 + r) * 64 + kk] +
                s_acc[(32 + r) * 64 + kk] + s_acc[(48 + r) * 64 + kk];
      v = msk ? -1e10f : wv * v;
      scores[((size_t)b * Nn + n0 + r) * Kk + kk] = v;
      if (v > m) { ssum = ssum * __expf(m - v) + 1.0f; m = v; }
      else ssum += __expf(v - m);
    }
    s_m[hs * 64 + k] = m; s_s[hs * 64 + k] = ssum;
    __syncthreads();
    if (t < 64) {
      float M = fmaxf(fmaxf(s_m[t], s_m[64 + t]), fmaxf(s_m[128 + t], s_m[192 + t]));
      float S = 0.f;
#pragma unroll
      for (int q = 0; q < 4; ++q) S += s_s[q * 64 + t] * __expf(s_m[q * 64 + t] - M);
      pmT[((size_t)b * 64 + ntile) * 64 + t] = M;
      psT[((size_t)b * 64 + ntile) * 64 + t] = S;
    }
  }
}

// ===========================================================================
// KD: kfr partials; softmax stats finalized inline.  grid B*8*4, 512 thr
// ===========================================================================
__global__ __launch_bounds__(512) void kD(
    const float* __restrict__ scores, const float* __restrict__ hs_rec,
    const float* __restrict__ pmT, const float* __restrict__ psT,
    float* __restrict__ kfrP)
{
  __shared__ float sP[2048];
  __shared__ float sM[64], sS[64], sFm[8], sFs[8];
  const int b = blockIdx.x >> 5;
  const int k8 = (blockIdx.x >> 2) & 7;
  const int ns = blockIdx.x & 3;
  const int t = threadIdx.x;
  const int h = t & 127, kq = t >> 7;
  const int n0 = ns * 256;

  // finalize per-k softmax stats (8 k's, 64 tiles) in two steps
  if (t < 64) {
    const int kk = t & 7, ch = t >> 3;
    const int kg = k8 * 8 + kk;
    float m = -3.0e38f, s = 0.f;
    for (int nt = ch * 8; nt < ch * 8 + 8; ++nt) {
      const float pm = pmT[((size_t)b * 64 + nt) * 64 + kg];
      const float ps = psT[((size_t)b * 64 + nt) * 64 + kg];
      if (pm > m) { s = s * __expf(m - pm) + ps; m = pm; }
      else s += ps * __expf(pm - m);
    }
    sM[t] = m; sS[t] = s;
  }
  __syncthreads();
  if (t < 8) {
    float M = -3.0e38f;
    for (int ch = 0; ch < 8; ++ch) M = fmaxf(M, sM[ch * 8 + t]);
    float S = 0.f;
    for (int ch = 0; ch < 8; ++ch) S += sS[ch * 8 + t] * __expf(sM[ch * 8 + t] - M);
    sFm[t] = M; sFs[t] = 1.0f / S;
  }
  __syncthreads();

  {
    const float* sc = scores + ((size_t)b * Nn + n0) * Kk + k8 * 8;
    for (int idx = t; idx < 2048; idx += 512) {
      const int n = idx >> 3, kk = idx & 7;
      sP[n * 8 + kk] = __expf(sc[(size_t)n * Kk + kk] - sFm[kk]) * sFs[kk];
    }
  }
  __syncthreads();
  const int kk0 = kq * 2;
  float a0 = 0.f, a1 = 0.f;
  const float* hr = hs_rec + ((size_t)b * Nn + n0) * Mm + h;
  for (int n = 0; n < 256; ++n) {
    const float hv = hr[(size_t)n * Mm];
    a0 += sP[n * 8 + kk0] * hv;
    a1 += sP[n * 8 + kk0 + 1] * hv;
  }
  const int k0 = k8 * 8 + kk0;
  kfrP[(((size_t)b * 4 + ns) * Kk + k0) * Mm + h] = a0;
  kfrP[(((size_t)b * 4 + ns) * Kk + k0 + 1) * Mm + h] = a1;
}

// ===========================================================================
// KE: final fused stage, block per b (1024 threads)
// ===========================================================================
__global__ __launch_bounds__(1024) void kE(
    const float* __restrict__ attl_part, const float* __restrict__ att_r,
    const float* __restrict__ la_lh, const float* __restrict__ kfrP,
    const float* __restrict__ kRT, const float* __restrict__ kR_b,
    const float* __restrict__ ra_rh, const float* __restrict__ lig_rep,
    const float* __restrict__ mapL_w, const float* __restrict__ mapL_b,
    const float* __restrict__ fin_w, const float* __restrict__ fin_b,
    float* __restrict__ out)
{
  const int b = blockIdx.x;
  const int t = threadIdx.x;
  const int h = t & 127, sg = t >> 7;   // 0..7
  __shared__ float s_attl[64];
  __shared__ float s_attr[Gg];
  __shared__ float s_pair[264];
  __shared__ float s_u[Mm];
  __shared__ float s_red[8][Mm];
  __shared__ float s5[16];

  if (t < 64) {
    float a = 0.f;
    for (int p = 0; p < 8; ++p) a += attl_part[(b * 8 + p) * 64 + t];
    s_attl[t] = a;
  }
  if (t < Gg) s_attr[t] = att_r[b * Gg + t];
  __syncthreads();

  // key_rep (attention part)
  {
    float acc = 0.f;
    for (int j = 0; j < 8; ++j) {
      const int k = sg * 8 + j;
      acc += s_attl[k] * la_lh[((size_t)b * Kk + k) * Mm + h];
    }
    s_red[sg][h] = acc;
  }
  __syncthreads();
  if (sg == 0) {
    float v = 0.f;
#pragma unroll
    for (int q = 0; q < 8; ++q) v += s_red[q][h];
    s_pair[h] = v;
  }
  __syncthreads();

  // u = sum_{ns,k} att_l[k] * kfrP[b, ns*64+k, h]
  {
    float acc = 0.f;
    for (int j = 0; j < 32; ++j) {
      const int row = sg * 32 + j;
      acc += s_attl[row & 63] * kfrP[((size_t)b * 256 + row) * Mm + h];
    }
    s_red[sg][h] = acc;
  }
  __syncthreads();
  if (sg == 0) {
    float v = 0.f;
#pragma unroll
    for (int q = 0; q < 8; ++q) v += s_red[q][h];
    s_u[h] = v;
  }
  __syncthreads();

  // kfr2 = u @ kRT + sA * kR_b, added to key_rep
  {
    float acc = 0.f;
    for (int j = 0; j < 16; ++j) {
      const int hp = sg * 16 + j;
      acc += s_u[hp] * kRT[(size_t)hp * Mm + h];
    }
    s_red[sg][h] = acc;
  }
  __syncthreads();
  if (sg == 0) {
    float sA = 0.f;
    for (int k2 = 0; k2 < 64; ++k2) sA += s_attl[k2];
    float v = 0.f;
#pragma unroll
    for (int q = 0; q < 8; ++q) v += s_red[q][h];
    s_pair[h] += v + sA * kR_b[h];
  }
  __syncthreads();

  // grid_rep
  {
    float acc = 0.f;
    for (int j = 0; j < 64; ++j) {
      const int g = sg * 64 + j;
      acc += s_attr[g] * ra_rh[((size_t)b * Gg + g) * Mm + h];
    }
    s_red[sg][h] = acc;
  }
  __syncthreads();
  if (sg == 0) {
    float v = 0.f;
#pragma unroll
    for (int q = 0; q < 8; ++q) v += s_red[q][h];
    s_pair[132 + h] = v;
  }
  if (t < 4) s_pair[128 + t] = lig_rep[b * 4 + t];
  __syncthreads();

  // mapL: 5 outputs over 260 inputs
  const int l = t >> 6, lane = t & 63;
  if (l < 5) {
    float acc = 0.f;
    for (int c = lane; c < 260; c += 64) acc += s_pair[c] * mapL_w[l * 260 + c];
    for (int off = 32; off; off >>= 1) acc += __shfl_xor(acc, off);
    if (lane == 0) s5[l] = acc + mapL_b[l];
  }
  __syncthreads();
  if (t == 0) {
    float o = fin_b[0];
    for (int l2 = 0; l2 < 5; ++l2) o += s5[l2] * fin_w[l2];
    out[b] = o;
  }
}

// ---------------------------------------------------------------------------
extern "C" void kernel_launch(void* const* d_in, const int* in_sizes, int n_in,
                              void* d_out, int out_size, void* d_ws, size_t ws_size,
                              hipStream_t stream) {
  const float* z       = (const float*)d_in[0];
  const float* hs_grid = (const float*)d_in[1];
  const float* hs_key  = (const float*)d_in[2];
  const float* lig_rep = (const float*)d_in[3];
  const float* hs_rec  = (const float*)d_in[4];
  const float* w_Rl    = (const float*)d_in[5];
  const int*   w_mask  = (const int*)d_in[6];
  const float* wra_w = (const float*)d_in[7];  const float* wra_b = (const float*)d_in[8];
  const float* wrh_w = (const float*)d_in[9];  const float* wrh_b = (const float*)d_in[10];
  const float* wla_w = (const float*)d_in[11]; const float* wla_b = (const float*)d_in[12];
  const float* wlh_w = (const float*)d_in[13]; const float* wlh_b = (const float*)d_in[14];
  const float* z1_w  = (const float*)d_in[15];
  const float* wcR_w = (const float*)d_in[17]; const float* wcR_b = (const float*)d_in[18];
  const float* wcl_w = (const float*)d_in[19]; const float* wcl_b = (const float*)d_in[20];
  const float* kR_w  = (const float*)d_in[21]; const float* kR_b  = (const float*)d_in[22];
  const float* mapL_w = (const float*)d_in[23]; const float* mapL_b = (const float*)d_in[24];
  const float* fin_w  = (const float*)d_in[25]; const float* fin_b  = (const float*)d_in[26];
  float* out = (float*)d_out;

  float* w = (float*)d_ws;
  float* wT    = w;                           // 7*16384 = 114688
  float* ra    = wT + 7 * 16384;              // 524288
  float* att   = ra + Bb * Gg * Mm;           // 262144
  float* laNum = att + Bb * Gg * Kk;          // 4194304  (dead after kB)
  float* laDen = laNum + Bb * NCH * Kk * Mm;  // 4194304  (dead after kB)
  float* la    = laDen + Bb * NCH * Kk * Mm;  // 65536
  float* attlP = la + Bb * Kk * Mm;           // 4096
  float* attrPM = attlP + Bb * 8 * 64;        // 4096
  float* attrPS = attrPM + Bb * 8 * 64;       // 4096
  float* att_r = attrPS + Bb * 8 * 64;        // 4096
  float* ra_rh = att_r + Bb * Gg;             // 524288
  float* la_lh = ra_rh + Bb * Gg * Mm;        // 65536
  float* Rh    = la_lh + Bb * Kk * Mm;        // 1048576
  float* lh    = Rh + Bb * Nn * Mm;           // 65536
  float* scores = lh + Bb * Kk * Mm;          // 524288

  // aliases into laNum/laDen (dead after kB's la-reduce)
  float* pmT  = laNum;                        // B*64*64 = 32768
  float* psT  = laNum + 32768;                // 32768
  float* kfrP = laDen;                        // B*4*K*M = 262144

  P7 ptrs;
  ptrs.p[0] = wra_w; ptrs.p[1] = wrh_w; ptrs.p[2] = wla_w; ptrs.p[3] = wlh_w;
  ptrs.p[4] = wcR_w; ptrs.p[5] = wcl_w; ptrs.p[6] = kR_w;

  kA<<<Bb * NCH + 112, 1024, 0, stream>>>(z, hs_grid, hs_key, z1_w, ptrs, wT,
                                          ra, att, laNum, laDen);
  kB<<<928, 256, 0, stream>>>(laNum, laDen, la, att, attlP, attrPM, attrPS,
                              hs_rec, hs_key, wT, wcR_b, wcl_b, Rh, lh);
  kC<<<864, 256, 0, stream>>>(att, attrPM, attrPS, att_r, ra, hs_grid, la, hs_key,
                              wT, wra_b, wrh_b, wla_b, wlh_b, ra_rh, la_lh,
                              Rh, lh, w_mask, w_Rl, scores, pmT, psT);
  kD<<<Bb * 8 * 4, 512, 0, stream>>>(scores, hs_rec, pmT, psT, kfrP);
  kE<<<Bb, 1024, 0, stream>>>(attlP, att_r, la_lh, kfrP, wT + 6 * 16384, kR_b,
                              ra_rh, lig_rep, mapL_w, mapL_b, fin_w, fin_b, out);
}

// Round 4
// 89.199 us; speedup vs baseline: 3.7179x; 1.1184x over previous
//
#include <hip/hip_runtime.h>

// Problem dims
#define Bb 8
#define Gg 512
#define Kk 64
#define Nn 1024
#define Mm 128
#define KM (Kk * Mm)      // 8192
#define GPB 16            // g per block in kA z-pass
#define NCH (Gg / GPB)    // 32 partial chunks

struct P7 { const float* p[7]; };

// ===========================================================================
// KA: z-pass (blocks 0..255) + 7x weight transpose (blocks 256..367)
//   ra[b,g,m], att[b,g,k], laNum/laDen partials per 16-g chunk
// ===========================================================================
__global__ __launch_bounds__(1024) void kA(
    const float* __restrict__ z, const float* __restrict__ hs_grid,
    const float* __restrict__ hs_key, const float* __restrict__ z1w,
    P7 ptrs, float* __restrict__ wT,
    float* __restrict__ raOut, float* __restrict__ attOut,
    float* __restrict__ laNum, float* __restrict__ laDen)
{
  __shared__ __align__(16) float smem[18432];   // 72 KB
  const int bid = blockIdx.x;
  const int t = threadIdx.x;

  if (bid >= Bb * NCH) {
    // ---- weight transpose: 112 blocks, 32x32 tiles ----
    float* tile = smem;                          // 32*33
    const int r = bid - Bb * NCH;
    const int mat = r >> 4, tl = r & 15;
    const int xo = (tl & 3) * 32, y0 = (tl >> 2) * 32;
    const int tx = t & 31, ty = t >> 5;
    const float* src = ptrs.p[mat];
    float* dst = wT + (size_t)mat * Mm * Mm;
    tile[ty * 33 + tx] = src[(size_t)(y0 + ty) * Mm + xo + tx];
    __syncthreads();
    dst[(size_t)(xo + ty) * Mm + y0 + tx] = tile[tx * 33 + ty];
    return;
  }

  float* s_hskey  = smem;            // 8192
  float* s_hsgrid = smem + 8192;     // 2048
  float* s_rn     = smem + 10240;    // 2 x 2048 (double buffered)
  float* s_rd     = smem + 14336;    // 2 x 2048

  const int b = bid >> 5;
  const int gblk = bid & 31;
  const int lane_m = t & 31;
  const int m4 = lane_m << 2;
  const int kgrp = t >> 5;           // 0..31
  const int wv = t >> 6;             // 0..15

  const float* hkb = hs_key + (size_t)b * KM;
  for (int idx = t; idx < KM; idx += 1024) s_hskey[idx] = hkb[idx];
  const float* hgb = hs_grid + ((size_t)b * Gg + gblk * GPB) * Mm;
  for (int idx = t; idx < GPB * Mm; idx += 1024) s_hsgrid[idx] = hgb[idx];

  const float zw0 = z1w[m4], zw1 = z1w[m4 + 1], zw2 = z1w[m4 + 2], zw3 = z1w[m4 + 3];

  float la_n[2][4], la_d[2][4];
#pragma unroll
  for (int i = 0; i < 2; ++i)
#pragma unroll
    for (int j = 0; j < 4; ++j) { la_n[i][j] = 0.f; la_d[i][j] = 0.f; }

  const float* zb = z + ((size_t)b * Gg + gblk * GPB) * (size_t)Mm * Kk;
  const int ofs0 = (kgrp * 2) * Mm + m4;
  const int ofs1 = ofs0 + Mm;
  float4 c0 = *reinterpret_cast<const float4*>(zb + ofs0);
  float4 c1 = *reinterpret_cast<const float4*>(zb + ofs1);

  __syncthreads();   // staging ready

  for (int gl = 0; gl < GPB; ++gl) {
    float4 n0 = c0, n1 = c1;
    if (gl < GPB - 1) {
      n0 = *reinterpret_cast<const float4*>(zb + (size_t)(gl + 1) * KM + ofs0);
      n1 = *reinterpret_cast<const float4*>(zb + (size_t)(gl + 1) * KM + ofs1);
    }
    const int g = gblk * GPB + gl;
    const float4 hg = *reinterpret_cast<const float4*>(s_hsgrid + gl * Mm + m4);
    float rn0 = 0, rn1 = 0, rn2 = 0, rn3 = 0, rd0 = 0, rd1 = 0, rd2 = 0, rd3 = 0;
#pragma unroll
    for (int i = 0; i < 2; ++i) {
      const float4 v = (i == 0) ? c0 : c1;
      const int k = kgrp * 2 + i;
      const float e0 = __expf(v.x), e1 = __expf(v.y), e2 = __expf(v.z), e3 = __expf(v.w);
      la_n[i][0] += e0 * hg.x; la_n[i][1] += e1 * hg.y; la_n[i][2] += e2 * hg.z; la_n[i][3] += e3 * hg.w;
      la_d[i][0] += e0;        la_d[i][1] += e1;        la_d[i][2] += e2;        la_d[i][3] += e3;
      const float4 hk = *reinterpret_cast<const float4*>(s_hskey + k * Mm + m4);
      rn0 += e0 * hk.x; rn1 += e1 * hk.y; rn2 += e2 * hk.z; rn3 += e3 * hk.w;
      rd0 += e0; rd1 += e1; rd2 += e2; rd3 += e3;
      float ap = v.x * zw0 + v.y * zw1 + v.z * zw2 + v.w * zw3;
      ap += __shfl_xor(ap, 16); ap += __shfl_xor(ap, 8); ap += __shfl_xor(ap, 4);
      ap += __shfl_xor(ap, 2);  ap += __shfl_xor(ap, 1);
      if (lane_m == 0) attOut[((size_t)b * Gg + g) * Kk + k] = ap;
    }
    rn0 += __shfl_xor(rn0, 32); rn1 += __shfl_xor(rn1, 32); rn2 += __shfl_xor(rn2, 32); rn3 += __shfl_xor(rn3, 32);
    rd0 += __shfl_xor(rd0, 32); rd1 += __shfl_xor(rd1, 32); rd2 += __shfl_xor(rd2, 32); rd3 += __shfl_xor(rd3, 32);
    float* rnB = s_rn + (gl & 1) * 2048;
    float* rdB = s_rd + (gl & 1) * 2048;
    if ((t & 63) < 32) {
      *reinterpret_cast<float4*>(rnB + wv * Mm + m4) = make_float4(rn0, rn1, rn2, rn3);
      *reinterpret_cast<float4*>(rdB + wv * Mm + m4) = make_float4(rd0, rd1, rd2, rd3);
    }
    __syncthreads();
    if (t < Mm) {
      float num = 0.f, den = 0.f;
#pragma unroll
      for (int ww = 0; ww < 16; ++ww) { num += rnB[ww * Mm + t]; den += rdB[ww * Mm + t]; }
      raOut[((size_t)b * Gg + g) * Mm + t] = num / den;
    }
    c0 = n0; c1 = n1;
  }

  const size_t base = ((size_t)(b * NCH + gblk)) * KM;
#pragma unroll
  for (int i = 0; i < 2; ++i) {
    const int k = kgrp * 2 + i;
    *reinterpret_cast<float4*>(laNum + base + k * Mm + m4) =
        make_float4(la_n[i][0], la_n[i][1], la_n[i][2], la_n[i][3]);
    *reinterpret_cast<float4*>(laDen + base + k * Mm + m4) =
        make_float4(la_d[i][0], la_d[i][1], la_d[i][2], la_d[i][3]);
  }
}

// ===========================================================================
// device helper: linear over 16 rows (256 threads)
// ===========================================================================
__device__ __forceinline__ void lin1_body(
    int r0, const float* __restrict__ in1, const float* __restrict__ W1T,
    const float* __restrict__ b1, float* __restrict__ out, float* smem)
{
  float* s1 = smem;            // 2048
  float* sacc = smem + 2048;   // 2048
  const int t = threadIdx.x;
  const int m = t & 127, hh = t >> 7;
  for (int idx = t; idx < 2048; idx += 256) s1[idx] = in1[(size_t)r0 * Mm + idx];
  __syncthreads();
  float acc[16];
#pragma unroll
  for (int r = 0; r < 16; ++r) acc[r] = 0.f;
  const int h0 = hh * 64;
  for (int h = h0; h < h0 + 64; ++h) {
    const float w1 = W1T[(size_t)h * Mm + m];
#pragma unroll
    for (int r = 0; r < 16; ++r) acc[r] += s1[r * Mm + h] * w1;
  }
  if (hh == 1) {
#pragma unroll
    for (int r = 0; r < 16; ++r) sacc[r * Mm + m] = acc[r];
  }
  __syncthreads();
  if (hh == 0) {
    const float bias = b1[m];
#pragma unroll
    for (int r = 0; r < 16; ++r) out[(size_t)(r0 + r) * Mm + m] = acc[r] + sacc[r * Mm + m] + bias;
  }
}

// ===========================================================================
// KB: [0,256) la-reduce | [256,320) att_l partials | [320,384) att_r partials
//     | [384,896) Rh linear | [896,928) lh linear          (256 threads)
// ===========================================================================
__global__ __launch_bounds__(256) void kB(
    const float* __restrict__ laNum, const float* __restrict__ laDen, float* __restrict__ la,
    const float* __restrict__ att, float* __restrict__ attlP,
    float* __restrict__ attrPM, float* __restrict__ attrPS,
    const float* __restrict__ hs_rec, const float* __restrict__ hs_key,
    const float* __restrict__ wT, const float* __restrict__ wcR_b, const float* __restrict__ wcl_b,
    float* __restrict__ Rh, float* __restrict__ lh)
{
  __shared__ __align__(16) float smem[4096];   // 16 KB
  const int bid = blockIdx.x;
  const int t = threadIdx.x;

  if (bid < 256) {
    const int idx = bid * 256 + t;
    const int b = idx >> 13, r = idx & 8191;
    const float* np = laNum + (size_t)b * NCH * KM + r;
    const float* dp = laDen + (size_t)b * NCH * KM + r;
    float num = 0.f, den = 0.f;
#pragma unroll 8
    for (int p = 0; p < NCH; ++p) { num += np[(size_t)p * KM]; den += dp[(size_t)p * KM]; }
    la[idx] = num / den;
  } else if (bid < 320) {
    const int blk = bid - 256;
    const int b = blk >> 3, p = blk & 7;
    const int w = t >> 6, lane = t & 63;
    float acc = 0.f;
    for (int j = 0; j < 16; ++j) {
      const int g = p * 64 + w * 16 + j;
      const float a = att[((size_t)b * Gg + g) * Kk + lane];
      float mx = a;
      for (int off = 32; off; off >>= 1) mx = fmaxf(mx, __shfl_xor(mx, off));
      const float e = __expf(a - mx);
      float s = e;
      for (int off = 32; off; off >>= 1) s += __shfl_xor(s, off);
      acc += e / s;
    }
    float* sred = smem;
    sred[w * 64 + lane] = acc;
    __syncthreads();
    if (t < 64) attlP[(b * 8 + p) * 64 + t] = sred[t] + sred[64 + t] + sred[128 + t] + sred[192 + t];
  } else if (bid < 384) {
    const int blk = bid - 320;
    const int b = blk >> 3, gc = blk & 7;
    const int k = t & 63, j4 = t >> 6;
    float m = -1e30f, s = 0.f;
    for (int j = 0; j < 16; ++j) {
      const int g = gc * 64 + j4 * 16 + j;
      const float a = att[((size_t)b * Gg + g) * Kk + k];
      if (a > m) { s = s * __expf(m - a) + 1.0f; m = a; }
      else s += __expf(a - m);
    }
    float* sm = smem;          // 256
    float* ss = smem + 256;    // 256
    sm[j4 * 64 + k] = m; ss[j4 * 64 + k] = s;
    __syncthreads();
    if (t < 64) {
      float M = sm[t];
      for (int q = 1; q < 4; ++q) M = fmaxf(M, sm[q * 64 + t]);
      float S = 0.f;
      for (int q = 0; q < 4; ++q) S += ss[q * 64 + t] * __expf(sm[q * 64 + t] - M);
      attrPM[(b * 8 + gc) * 64 + t] = M;
      attrPS[(b * 8 + gc) * 64 + t] = S;
    }
  } else if (bid < 896) {
    lin1_body((bid - 384) * 16, hs_rec, wT + 4 * 16384, wcR_b, Rh, smem);
  } else {
    lin1_body((bid - 896) * 16, hs_key, wT + 5 * 16384, wcl_b, lh, smem);
  }
}

// ===========================================================================
// KC: [0,64) att_r final | [64,576) scores + per-tile softmax partials
// ===========================================================================
__global__ __launch_bounds__(256) void kC(
    const float* __restrict__ att, const float* __restrict__ attrPM, const float* __restrict__ attrPS,
    float* __restrict__ att_r,
    const float* __restrict__ Rh, const float* __restrict__ lh,
    const int* __restrict__ mask, const float* __restrict__ wRl,
    float* __restrict__ scores, float* __restrict__ pmT, float* __restrict__ psT)
{
  __shared__ __align__(16) float smem[14912];   // 58.25 KB
  const int bid = blockIdx.x;
  const int t = threadIdx.x;

  if (bid < 64) {
    const int b = bid >> 3, gc = bid & 7;
    const int k = t & 63, grp = t >> 6;
    float* Mx = smem;
    float* S = smem + 64;
    if (t < 64) {
      float M = -1e30f;
      for (int p = 0; p < 8; ++p) M = fmaxf(M, attrPM[(b * 8 + p) * 64 + t]);
      float s = 0.f;
      for (int p = 0; p < 8; ++p) s += attrPS[(b * 8 + p) * 64 + t] * __expf(attrPM[(b * 8 + p) * 64 + t] - M);
      Mx[t] = M; S[t] = s;
    }
    __syncthreads();
    const float Mk = Mx[k], Sk = S[k];
    for (int j = 0; j < 16; ++j) {
      const int g = gc * 64 + grp * 16 + j;
      float p = __expf(att[((size_t)b * Gg + g) * Kk + k] - Mk) / Sk;
      for (int off = 32; off; off >>= 1) p += __shfl_xor(p, off);
      if (k == 0) att_r[b * Gg + g] = p;
    }
  } else {
    const int vb = bid - 64;
    const int b = vb >> 6, ntile = vb & 63;
    const int n0 = ntile * 16;
    const int k = t & 63, hs = t >> 6;
    float* s_rh  = smem;                 // 2048
    float* s_lh  = smem + 2048;          // 64*129 = 8256
    float* s_acc = smem + 10304;         // 4096
    float* s_m   = smem + 14400;         // 256
    float* s_s   = smem + 14656;         // 256
    for (int idx = t; idx < 2048; idx += 256)
      s_rh[idx] = Rh[((size_t)b * Nn + n0) * Mm + idx];
    for (int idx = t; idx < 8192; idx += 256)
      s_lh[(idx >> 7) * 129 + (idx & 127)] = lh[(size_t)b * Kk * Mm + idx];
    __syncthreads();
    float acc[16];
#pragma unroll
    for (int r = 0; r < 16; ++r) acc[r] = 0.f;
    for (int h = hs * 32; h < hs * 32 + 32; ++h) {
      const float lv = s_lh[k * 129 + h];
#pragma unroll
      for (int r = 0; r < 16; ++r) acc[r] += s_rh[r * Mm + h] * lv;
    }
#pragma unroll
    for (int r = 0; r < 16; ++r) s_acc[(hs * 16 + r) * 64 + k] = acc[r];
    __syncthreads();
    const float wv = wRl[0];
    const bool msk = (mask[b * Kk + k] == 0);
    float m = -3.0e38f, ssum = 0.f;
    for (int q = 0; q < 4; ++q) {
      const int idx = q * 256 + t;
      const int r = idx >> 6, kk = idx & 63;
      float v = s_acc[r * 64 + kk] + s_acc[(16 + r) * 64 + kk] +
                s_acc[(32 + r) * 64 + kk] + s_acc[(48 + r) * 64 + kk];
      v = msk ? -1e10f : wv * v;
      scores[((size_t)b * Nn + n0 + r) * Kk + kk] = v;
      if (v > m) { ssum = ssum * __expf(m - v) + 1.0f; m = v; }
      else ssum += __expf(v - m);
    }
    s_m[hs * 64 + k] = m; s_s[hs * 64 + k] = ssum;
    __syncthreads();
    if (t < 64) {
      float M = fmaxf(fmaxf(s_m[t], s_m[64 + t]), fmaxf(s_m[128 + t], s_m[192 + t]));
      float S = 0.f;
#pragma unroll
      for (int q = 0; q < 4; ++q) S += s_s[q * 64 + t] * __expf(s_m[q * 64 + t] - M);
      pmT[((size_t)b * 64 + ntile) * 64 + t] = M;
      psT[((size_t)b * 64 + ntile) * 64 + t] = S;
    }
  }
}

// ===========================================================================
// KD: weighted-sum partial reductions (512 threads)
//  [0,64)   (b, nc): q[n]=sum_k att_l*P;  uP[b,nc,h] = sum_n q*hs_rec
//  [64,128) (b, gc): w1P = sum_g att_r*ra, w2P = sum_g att_r*hs_grid, w0P = sum att_r
//  [128,136) b:      v1 = sum_k att_l*la, v2 = sum_k att_l*hs_key, sA = sum att_l
// ===========================================================================
__global__ __launch_bounds__(512) void kD(
    const float* __restrict__ scores, const float* __restrict__ hs_rec,
    const float* __restrict__ pmT, const float* __restrict__ psT,
    const float* __restrict__ attlP, const float* __restrict__ att_r,
    const float* __restrict__ ra, const float* __restrict__ hs_grid,
    const float* __restrict__ la, const float* __restrict__ hs_key,
    float* __restrict__ uP, float* __restrict__ w1P, float* __restrict__ w2P,
    float* __restrict__ w0P, float* __restrict__ v1, float* __restrict__ v2,
    float* __restrict__ sAv)
{
  __shared__ float sm[1280];
  __shared__ float s_attl[64];
  __shared__ float sM[64], sSi[64];
  const int bid = blockIdx.x;
  const int t = threadIdx.x;

  if (bid < 64) {
    const int b = bid >> 3, nc = bid & 7;
    if (t < 64) {
      float a = 0.f;
      for (int p = 0; p < 8; ++p) a += attlP[(b * 8 + p) * 64 + t];
      s_attl[t] = a;
      float M = -3.0e38f;
      for (int nt = 0; nt < 64; ++nt) M = fmaxf(M, pmT[((size_t)b * 64 + nt) * 64 + t]);
      float S = 0.f;
      for (int nt = 0; nt < 64; ++nt)
        S += psT[((size_t)b * 64 + nt) * 64 + t] * __expf(pmT[((size_t)b * 64 + nt) * 64 + t] - M);
      sM[t] = M; sSi[t] = 1.0f / S;
    }
    __syncthreads();
    // q[n] over this block's 128 n's
    const int n = t >> 2, ks = t & 3;
    const float* sc = scores + ((size_t)b * Nn + nc * 128 + n) * Kk + ks * 16;
    float qp = 0.f;
#pragma unroll
    for (int j = 0; j < 16; ++j) {
      const int k = ks * 16 + j;
      qp += s_attl[k] * __expf(sc[j] - sM[k]) * sSi[k];
    }
    sm[n * 4 + ks] = qp;
    __syncthreads();
    float* q = sm + 512;
    if (t < 128) q[t] = sm[t * 4] + sm[t * 4 + 1] + sm[t * 4 + 2] + sm[t * 4 + 3];
    __syncthreads();
    // uP[h] = sum_n q[n] * hs_rec[b, nc*128+n, h]
    const int h = t & 127, nq = t >> 7;
    float acc = 0.f;
    const float* hr = hs_rec + ((size_t)b * Nn + nc * 128 + nq * 32) * Mm + h;
    for (int j = 0; j < 32; ++j) acc += q[nq * 32 + j] * hr[(size_t)j * Mm];
    float* red = sm + 640;   // needs q intact: q at 512..640, red at 640..1152
    red[nq * 128 + h] = acc;
    __syncthreads();
    if (t < 128) uP[((size_t)b * 8 + nc) * 128 + t] = red[t] + red[128 + t] + red[256 + t] + red[384 + t];
  } else if (bid < 128) {
    const int blk = bid - 64;
    const int b = blk >> 3, gc = blk & 7;
    float* s_ar = sm + 1152;   // 64
    if (t < 64) s_ar[t] = att_r[b * Gg + gc * 64 + t];
    __syncthreads();
    const int h = t & 127, gq = t >> 7;
    float a1 = 0.f, a2 = 0.f;
    const float* rp = ra + ((size_t)b * Gg + gc * 64 + gq * 16) * Mm + h;
    const float* gp = hs_grid + ((size_t)b * Gg + gc * 64 + gq * 16) * Mm + h;
    for (int j = 0; j < 16; ++j) {
      const float w = s_ar[gq * 16 + j];
      a1 += w * rp[(size_t)j * Mm];
      a2 += w * gp[(size_t)j * Mm];
    }
    float* r1 = sm;        // 512
    float* r2 = sm + 512;  // 512
    r1[gq * 128 + h] = a1; r2[gq * 128 + h] = a2;
    __syncthreads();
    if (t < 128) {
      w1P[((size_t)b * 8 + gc) * 128 + t] = r1[t] + r1[128 + t] + r1[256 + t] + r1[384 + t];
      w2P[((size_t)b * 8 + gc) * 128 + t] = r2[t] + r2[128 + t] + r2[256 + t] + r2[384 + t];
    }
    if (t == 0) {
      float s = 0.f;
      for (int j = 0; j < 64; ++j) s += s_ar[j];
      w0P[b * 8 + gc] = s;
    }
  } else {
    const int b = bid - 128;
    if (t < 64) {
      float a = 0.f;
      for (int p = 0; p < 8; ++p) a += attlP[(b * 8 + p) * 64 + t];
      s_attl[t] = a;
    }
    __syncthreads();
    const int h = t & 127, kq = t >> 7;
    float a1 = 0.f, a2 = 0.f;
    const float* lp = la + ((size_t)b * Kk + kq * 16) * Mm + h;
    const float* kp = hs_key + ((size_t)b * Kk + kq * 16) * Mm + h;
    for (int j = 0; j < 16; ++j) {
      const float w = s_attl[kq * 16 + j];
      a1 += w * lp[(size_t)j * Mm];
      a2 += w * kp[(size_t)j * Mm];
    }
    float* r1 = sm;
    float* r2 = sm + 512;
    r1[kq * 128 + h] = a1; r2[kq * 128 + h] = a2;
    __syncthreads();
    if (t < 128) {
      v1[b * 128 + t] = r1[t] + r1[128 + t] + r1[256 + t] + r1[384 + t];
      v2[b * 128 + t] = r2[t] + r2[128 + t] + r2[256 + t] + r2[384 + t];
    }
    if (t == 0) {
      float s = 0.f;
      for (int j = 0; j < 64; ++j) s += s_attl[j];
      sAv[b] = s;
    }
  }
}

// ===========================================================================
// KE: finale per b (256 threads): 5 matvecs + pair -> mapL -> fin
// ===========================================================================
__global__ __launch_bounds__(256) void kE(
    const float* __restrict__ uP, const float* __restrict__ w1P, const float* __restrict__ w2P,
    const float* __restrict__ w0P, const float* __restrict__ v1, const float* __restrict__ v2,
    const float* __restrict__ sAv, const float* __restrict__ wT,
    const float* __restrict__ wra_b, const float* __restrict__ wrh_b,
    const float* __restrict__ wla_b, const float* __restrict__ wlh_b,
    const float* __restrict__ kR_b, const float* __restrict__ lig_rep,
    const float* __restrict__ mapL_w, const float* __restrict__ mapL_b,
    const float* __restrict__ fin_w, const float* __restrict__ fin_b,
    float* __restrict__ out)
{
  __shared__ float sV1[128], sV2[128], sU[128], sW1[128], sW2[128];
  __shared__ float sPair[260];
  __shared__ float sRed[2][2][128];
  __shared__ float s5[8];
  __shared__ float sSc[2];
  const int b = blockIdx.x, t = threadIdx.x;
  const int m = t & 127, hf = t >> 7;

  if (t < 128) {
    float u = 0.f, w1 = 0.f, w2 = 0.f;
    for (int c = 0; c < 8; ++c) {
      u  += uP[((size_t)b * 8 + c) * 128 + t];
      w1 += w1P[((size_t)b * 8 + c) * 128 + t];
      w2 += w2P[((size_t)b * 8 + c) * 128 + t];
    }
    sU[t] = u; sW1[t] = w1; sW2[t] = w2;
    sV1[t] = v1[b * 128 + t]; sV2[t] = v2[b * 128 + t];
  }
  if (t == 0) {
    float s = 0.f;
    for (int c = 0; c < 8; ++c) s += w0P[b * 8 + c];
    sSc[0] = s;           // sR = sum att_r
    sSc[1] = sAv[b];      // sA = sum att_l
  }
  __syncthreads();

  const float* wraT = wT;
  const float* wrhT = wT + 1 * 16384;
  const float* wlaT = wT + 2 * 16384;
  const float* wlhT = wT + 3 * 16384;
  const float* kRT  = wT + 6 * 16384;
  float key = 0.f, grd = 0.f;
  for (int h = hf * 64; h < hf * 64 + 64; ++h) {
    key += sV1[h] * wlaT[h * Mm + m] + sV2[h] * wlhT[h * Mm + m] + sU[h] * kRT[h * Mm + m];
    grd += sW1[h] * wraT[h * Mm + m] + sW2[h] * wrhT[h * Mm + m];
  }
  sRed[0][hf][m] = key; sRed[1][hf][m] = grd;
  __syncthreads();
  if (t < 128) {
    const float sR = sSc[0], sA = sSc[1];
    sPair[t] = sRed[0][0][t] + sRed[0][1][t] + sA * (wla_b[t] + wlh_b[t] + kR_b[t]);
    sPair[132 + t] = sRed[1][0][t] + sRed[1][1][t] + sR * (wra_b[t] + wrh_b[t]);
  }
  if (t < 4) sPair[128 + t] = lig_rep[b * 4 + t];
  __syncthreads();

  const int wv = t >> 6, lane = t & 63;
  for (int l = wv; l < 5; l += 4) {
    float acc = 0.f;
    for (int c = lane; c < 260; c += 64) acc += sPair[c] * mapL_w[l * 260 + c];
    for (int off = 32; off; off >>= 1) acc += __shfl_xor(acc, off);
    if (lane == 0) s5[l] = acc + mapL_b[l];
  }
  __syncthreads();
  if (t == 0) {
    float o = fin_b[0];
    for (int l = 0; l < 5; ++l) o += s5[l] * fin_w[l];
    out[b] = o;
  }
}

// ---------------------------------------------------------------------------
extern "C" void kernel_launch(void* const* d_in, const int* in_sizes, int n_in,
                              void* d_out, int out_size, void* d_ws, size_t ws_size,
                              hipStream_t stream) {
  const float* z       = (const float*)d_in[0];
  const float* hs_grid = (const float*)d_in[1];
  const float* hs_key  = (const float*)d_in[2];
  const float* lig_rep = (const float*)d_in[3];
  const float* hs_rec  = (const float*)d_in[4];
  const float* w_Rl    = (const float*)d_in[5];
  const int*   w_mask  = (const int*)d_in[6];
  const float* wra_w = (const float*)d_in[7];  const float* wra_b = (const float*)d_in[8];
  const float* wrh_w = (const float*)d_in[9];  const float* wrh_b = (const float*)d_in[10];
  const float* wla_w = (const float*)d_in[11]; const float* wla_b = (const float*)d_in[12];
  const float* wlh_w = (const float*)d_in[13]; const float* wlh_b = (const float*)d_in[14];
  const float* z1_w  = (const float*)d_in[15];
  const float* wcR_w = (const float*)d_in[17]; const float* wcR_b = (const float*)d_in[18];
  const float* wcl_w = (const float*)d_in[19]; const float* wcl_b = (const float*)d_in[20];
  const float* kR_w  = (const float*)d_in[21]; const float* kR_b  = (const float*)d_in[22];
  const float* mapL_w = (const float*)d_in[23]; const float* mapL_b = (const float*)d_in[24];
  const float* fin_w  = (const float*)d_in[25]; const float* fin_b  = (const float*)d_in[26];
  float* out = (float*)d_out;

  float* w = (float*)d_ws;
  float* wT    = w;                           // 7*16384
  float* ra    = wT + 7 * 16384;              // B*G*M = 524288
  float* att   = ra + Bb * Gg * Mm;           // B*G*K = 262144
  float* laNum = att + Bb * Gg * Kk;          // B*NCH*K*M = 2097152 (dead after kB)
  float* laDen = laNum + Bb * NCH * Kk * Mm;  // 2097152 (dead after kB)
  float* la    = laDen + Bb * NCH * Kk * Mm;  // 65536
  float* attlP = la + Bb * Kk * Mm;           // 4096
  float* attrPM = attlP + Bb * 8 * 64;        // 4096
  float* attrPS = attrPM + Bb * 8 * 64;       // 4096
  float* att_r = attrPS + Bb * 8 * 64;        // 4096
  float* Rh    = att_r + Bb * Gg;             // B*N*M = 1048576
  float* lh    = Rh + Bb * Nn * Mm;           // 65536
  float* scores = lh + Bb * Kk * Mm;          // B*N*K = 524288

  // aliases into laNum (dead after kB)
  float* pmT  = laNum;                        // 32768
  float* psT  = laNum + 32768;                // 32768
  float* uP   = laNum + 65536;                // B*8*128 = 8192
  float* w1P  = laNum + 73728;                // 8192
  float* w2P  = laNum + 81920;                // 8192
  float* w0P  = laNum + 90112;                // 64
  float* v1   = laNum + 90176;                // 1024
  float* v2   = laNum + 91200;                // 1024
  float* sAv  = laNum + 92224;                // 8

  P7 ptrs;
  ptrs.p[0] = wra_w; ptrs.p[1] = wrh_w; ptrs.p[2] = wla_w; ptrs.p[3] = wlh_w;
  ptrs.p[4] = wcR_w; ptrs.p[5] = wcl_w; ptrs.p[6] = kR_w;

  kA<<<Bb * NCH + 112, 1024, 0, stream>>>(z, hs_grid, hs_key, z1_w, ptrs, wT,
                                          ra, att, laNum, laDen);
  kB<<<928, 256, 0, stream>>>(laNum, laDen, la, att, attlP, attrPM, attrPS,
                              hs_rec, hs_key, wT, wcR_b, wcl_b, Rh, lh);
  kC<<<576, 256, 0, stream>>>(att, attrPM, attrPS, att_r, Rh, lh,
                              w_mask, w_Rl, scores, pmT, psT);
  kD<<<136, 512, 0, stream>>>(scores, hs_rec, pmT, psT, attlP, att_r,
                              ra, hs_grid, la, hs_key,
                              uP, w1P, w2P, w0P, v1, v2, sAv);
  kE<<<Bb, 256, 0, stream>>>(uP, w1P, w2P, w0P, v1, v2, sAv, wT,
                             wra_b, wrh_b, wla_b, wlh_b, kR_b, lig_rep,
                             mapL_w, mapL_b, fin_w, fin_b, out);
}